// Round 14
// baseline (320.054 us; speedup 1.0000x reference)
//
#include <hip/hip_runtime.h>
#include <hip/hip_bf16.h>

// S4 (DPLR) forward, B=8 L=2048 IN=OUT=64 H=128 N=64, 4 layers.
// R14: conv = half-size-complex real FFT (R10's verified untangle/Kd4 pairing)
// with an ALL-ACTIVE (8,8,8,4) factorization — fixes R10's t<128 idling.
// One channel/block, grid 1024 (4 blocks/CU), 11.3K butterflies (was 24.6K),
// LDS 17.4 KB. Fwd pass A pruned (zero upper half), inv pass A' pruned to
// needed outputs. kfft stores Kd4 pairs. prep/mlp/decoder = R13.

#define Bsz 8
#define Lseq 2048
#define Hdim 128
#define Npol 64
#define NLAYERS 4

typedef __bf16 bf16x8 __attribute__((ext_vector_type(8)));
typedef float f32x16 __attribute__((ext_vector_type(16)));

__device__ __forceinline__ float fast_rcp(float x) { return __builtin_amdgcn_rcpf(x); }
__device__ __forceinline__ float fast_rsq(float x) { return __builtin_amdgcn_rsqf(x); }

__device__ __forceinline__ float2 cmulf(float2 a, float2 b) {
    return make_float2(a.x * b.x - a.y * b.y, a.x * b.y + a.y * b.x);
}
__device__ __forceinline__ float2 cmulc(float2 a, float2 b) {  // a * conj(b)
    return make_float2(a.x * b.x + a.y * b.y, a.y * b.x - a.x * b.y);
}

__device__ __forceinline__ float gelu_f(float v) {
    float z = 0.7978845608028654f * (v + 0.044715f * v * v * v);
    float e = __expf(2.0f * z);
    return v - v * fast_rcp(e + 1.0f);
}

// XOR swizzle for the kfft 4096 (16x16x16) array.
__device__ __forceinline__ int sw(int i) { return (i & ~15) | ((i ^ (i >> 4)) & 15); }
// Pad index for conv's 2048 array (strides 1/4/32/256, <=2-way for most passes).
__device__ __forceinline__ int ph(int i) { return i + (i >> 4); }

static __device__ const float W16R[8] = {1.f, 0.9238795325f, 0.7071067812f, 0.3826834324f,
                                         0.f, -0.3826834324f, -0.7071067812f, -0.9238795325f};
static __device__ const float W16I[8] = {0.f, -0.3826834324f, -0.7071067812f, -0.9238795325f,
                                         -1.f, -0.9238795325f, -0.7071067812f, -0.3826834324f};
static __device__ const int BR4[16] = {0, 8, 4, 12, 2, 10, 6, 14, 1, 9, 5, 13, 3, 11, 7, 15};
static __device__ const int BR3[8] = {0, 4, 2, 6, 1, 5, 3, 7};

__device__ __forceinline__ float2 twget(const float2* __restrict__ tw, int e) {
    float2 w = tw[e & 2047];
    if (e & 2048) { w.x = -w.x; w.y = -w.y; }
    return w;
}

template <bool INV>
__device__ __forceinline__ void fft16_dif(float2 v[16]) {
#pragma unroll
    for (int mi = 0; mi < 4; mi++) {
        const int m = 8 >> mi;
#pragma unroll
        for (int g = 0; g < 16; g += 2 * m) {
#pragma unroll
            for (int j = 0; j < m; j++) {
                float wr = W16R[j << mi];
                float wi = INV ? -W16I[j << mi] : W16I[j << mi];
                float2 a = v[g + j], b = v[g + j + m];
                float dx = a.x - b.x, dy = a.y - b.y;
                v[g + j] = make_float2(a.x + b.x, a.y + b.y);
                v[g + j + m] = make_float2(dx * wr - dy * wi, dx * wi + dy * wr);
            }
        }
    }
}

template <bool INV>
__device__ __forceinline__ void fft8_dif(float2 v[8]) {
#pragma unroll
    for (int mi = 0; mi < 3; mi++) {
        const int m = 4 >> mi;
#pragma unroll
        for (int g = 0; g < 8; g += 2 * m) {
#pragma unroll
            for (int j = 0; j < m; j++) {
                float wr = W16R[j << (mi + 1)];
                float wi = INV ? -W16I[j << (mi + 1)] : W16I[j << (mi + 1)];
                float2 a = v[g + j], b = v[g + j + m];
                float dx = a.x - b.x, dy = a.y - b.y;
                v[g + j] = make_float2(a.x + b.x, a.y + b.y);
                v[g + j + m] = make_float2(dx * wr - dy * wi, dx * wi + dy * wr);
            }
        }
    }
}

template <bool INV>
__device__ __forceinline__ void fft8_dit(float2 v[8]) {
#pragma unroll
    for (int mi = 2; mi >= 0; mi--) {
        const int m = 4 >> mi;
#pragma unroll
        for (int g = 0; g < 8; g += 2 * m) {
#pragma unroll
            for (int j = 0; j < m; j++) {
                float wr = W16R[j << (mi + 1)];
                float wi = INV ? -W16I[j << (mi + 1)] : W16I[j << (mi + 1)];
                float2 a = v[g + j], b = v[g + j + m];
                float bx = b.x * wr - b.y * wi, by = b.x * wi + b.y * wr;
                v[g + j] = make_float2(a.x + bx, a.y + by);
                v[g + j + m] = make_float2(a.x - bx, a.y - by);
            }
        }
    }
}

// radix-4 DIF, no twiddle, output digit-reversed {0,2,1,3}
__device__ __forceinline__ void fft4_dif(float2 v[4]) {
    float2 u0 = make_float2(v[0].x + v[2].x, v[0].y + v[2].y);
    float2 u2 = make_float2(v[0].x - v[2].x, v[0].y - v[2].y);
    float2 u1 = make_float2(v[1].x + v[3].x, v[1].y + v[3].y);
    float2 d3 = make_float2(v[1].x - v[3].x, v[1].y - v[3].y);
    float2 u3 = make_float2(d3.y, -d3.x);  // * (0,-1)
    v[0] = make_float2(u0.x + u1.x, u0.y + u1.y);
    v[1] = make_float2(u0.x - u1.x, u0.y - u1.y);
    v[2] = make_float2(u2.x + u3.x, u2.y + u3.y);
    v[3] = make_float2(u2.x - u3.x, u2.y - u3.y);
}

// radix-4 DIT with conj twiddles, digit-reversed in -> natural out
__device__ __forceinline__ void fft4_dit(float2 v[4]) {
    float2 u0 = make_float2(v[0].x + v[1].x, v[0].y + v[1].y);
    float2 u1 = make_float2(v[0].x - v[1].x, v[0].y - v[1].y);
    float2 u2 = make_float2(v[2].x + v[3].x, v[2].y + v[3].y);
    float2 u3 = make_float2(v[2].x - v[3].x, v[2].y - v[3].y);
    float2 b = make_float2(-u3.y, u3.x);  // * conj(0,-1) = * (0,1)
    v[0] = make_float2(u0.x + u2.x, u0.y + u2.y);
    v[2] = make_float2(u0.x - u2.x, u0.y - u2.y);
    v[1] = make_float2(u1.x + b.x, u1.y + b.y);
    v[3] = make_float2(u1.x - b.x, u1.y - b.y);
}

// Pass A of the zero-padded (upper half) forward 4096 FFT, input in registers (kfft).
__device__ __forceinline__ void fft4096_passA_hz(float2* data, const float2* __restrict__ tw,
                                                 int t, const float2 vin[8]) {
    float2 v[16];
#pragma unroll
    for (int j = 0; j < 8; j++) v[j] = vin[j];
#pragma unroll
    for (int j = 0; j < 8; j++)
        v[j + 8] = cmulf(v[j], make_float2(W16R[j], W16I[j]));
#pragma unroll
    for (int mi = 1; mi < 4; mi++) {
        const int m = 8 >> mi;
#pragma unroll
        for (int g = 0; g < 16; g += 2 * m) {
#pragma unroll
            for (int j = 0; j < m; j++) {
                float wr = W16R[j << mi], wi = W16I[j << mi];
                float2 a = v[g + j], b = v[g + j + m];
                float dx = a.x - b.x, dy = a.y - b.y;
                v[g + j] = make_float2(a.x + b.x, a.y + b.y);
                v[g + j + m] = make_float2(dx * wr - dy * wi, dx * wi + dy * wr);
            }
        }
    }
#pragma unroll
    for (int i = 1; i < 16; i++) v[i] = cmulf(v[i], twget(tw, t * BR4[i]));
#pragma unroll
    for (int i = 0; i < 16; i++) data[sw(i * 256 + t)] = v[i];
}

// Passes B and C of the forward 4096 FFT (leading barrier included) (kfft).
__device__ __forceinline__ void fft4096_fwd_BC(float2* data, const float2* __restrict__ tw, int t) {
    __syncthreads();
    {
        int j0 = t & 15;
        int base = (t >> 4) * 256 + j0;
        float2 v[16];
#pragma unroll
        for (int k = 0; k < 16; k++) v[k] = data[sw(base + 16 * k)];
        fft16_dif<false>(v);
#pragma unroll
        for (int i = 1; i < 16; i++) v[i] = cmulf(v[i], twget(tw, 16 * j0 * BR4[i]));
#pragma unroll
        for (int i = 0; i < 16; i++) data[sw(base + 16 * i)] = v[i];
    }
    __syncthreads();
    {
        float2 v[16];
#pragma unroll
        for (int k = 0; k < 16; k++) v[k] = data[sw(t * 16 + k)];
        fft16_dif<false>(v);
#pragma unroll
        for (int i = 0; i < 16; i++) data[sw(t * 16 + i)] = v[i];
    }
    __syncthreads();
}

// ---------------- prep: twiddle + weight-bf16 + spectrum, one launch ----------------
__global__ __launch_bounds__(256, 4) void prep_kernel(const float* __restrict__ lam_re,
                                                      const float* __restrict__ lam_im,
                                                      const float* __restrict__ p_re,
                                                      const float* __restrict__ p_im,
                                                      const float* __restrict__ b_re,
                                                      const float* __restrict__ b_im,
                                                      const float* __restrict__ c_re,
                                                      const float* __restrict__ c_im,
                                                      const float* __restrict__ log_step,
                                                      const float* __restrict__ w1,
                                                      const float* __restrict__ w2,
                                                      float2* __restrict__ tw,
                                                      __bf16* __restrict__ wbf,
                                                      float2* __restrict__ at_roots) {
    int bid = blockIdx.x, t = threadIdx.x;
    if (bid < 8) {
        int k = bid * 256 + t;
        if (k < 2048) {
            double a = -6.283185307179586476925286766559 * (double)k / 4096.0;
            tw[k] = make_float2((float)cos(a), (float)sin(a));
        }
        return;
    }
    if (bid < 264) {
        int i = (bid - 8) * 256 + t;
        int layer = i >> 14, rem = i & 16383;
        wbf[((size_t)layer * 2) * 16384 + rem] = (__bf16)w1[i];
        wbf[((size_t)layer * 2 + 1) * 16384 + rem] = (__bf16)w2[i];
        return;
    }
    int s = bid - 264;
    int h = s & 127, layer = (s >> 7) & 3;
    int l0 = 512 * (s >> 9);
    __shared__ __align__(16) float4 polA[Npol];
    __shared__ __align__(16) float4 polB[Npol];
    __shared__ float n11S[Npol];
    int baseP = (layer * Hdim + h) * Npol;
    if (t < Npol) {
        int n = t;
        float lr = lam_re[baseP + n], li = lam_im[baseP + n];
        float pr = p_re[baseP + n], pi = p_im[baseP + n];
        float br = b_re[baseP + n], bi = b_im[baseP + n];
        float cr = c_re[baseP + n], ci = c_im[baseP + n];
        polA[n] = make_float4(lr, li, cr * br + ci * bi, cr * bi - ci * br);
        polB[n] = make_float4(cr * pr + ci * pi, cr * pi - ci * pr,
                              pr * br + pi * bi, pr * bi - pi * br);
        n11S[n] = pr * pr + pi * pi;
    }
    __syncthreads();
    float step = expf(log_step[layer * Hdim + h]);
    float gs = 2.0f / step;

    float gr[2], gi[2];
#pragma unroll
    for (int j = 0; j < 2; j++) {
        int l = l0 + t + 256 * j;
        float ang = -6.283185307179586f * (float)l / (float)Lseq;
        float wr = cosf(ang), wi = sinf(ang);  // fp32 omega on purpose (range)
        float dr = 1.0f + wr, di = wi;
        float invd2 = fast_rcp(dr * dr + di * di);
        float nr = 1.0f - wr, ni = -wi;
        gr[j] = gs * (nr * dr + ni * di) * invd2;
        gi[j] = gs * (ni * dr - nr * di) * invd2;
    }
    float k00x[2] = {0, 0}, k00y[2] = {0, 0};
    float k01x[2] = {0, 0}, k01y[2] = {0, 0};
    float k10x[2] = {0, 0}, k10y[2] = {0, 0};
    float k11x[2] = {0, 0}, k11y[2] = {0, 0};
#pragma unroll 4
    for (int n = 0; n < Npol; n++) {
        float4 A = polA[n];
        float4 B = polB[n];
        float n11 = n11S[n];
#pragma unroll
        for (int j = 0; j < 2; j++) {
            float er = gr[j] - A.x, ei = gi[j] - A.y;
            float inv2 = fast_rcp(fmaf(er, er, ei * ei));
            float ir = er * inv2;
            float mi = ei * inv2;
            k00x[j] = fmaf(A.z, ir, fmaf(A.w, mi, k00x[j]));
            k00y[j] = fmaf(A.w, ir, fmaf(-A.z, mi, k00y[j]));
            k01x[j] = fmaf(B.x, ir, fmaf(B.y, mi, k01x[j]));
            k01y[j] = fmaf(B.y, ir, fmaf(-B.x, mi, k01y[j]));
            k10x[j] = fmaf(B.z, ir, fmaf(B.w, mi, k10x[j]));
            k10y[j] = fmaf(B.w, ir, fmaf(-B.z, mi, k10y[j]));
            k11x[j] = fmaf(n11, ir, k11x[j]);
            k11y[j] = fmaf(-n11, mi, k11y[j]);
        }
    }
#pragma unroll
    for (int j = 0; j < 2; j++) {
        int l = l0 + t + 256 * j;
        float ang = -6.283185307179586f * (float)l / (float)Lseq;
        float wr = cosf(ang), wi = sinf(ang);
        float dr = 1.0f + wr, di = wi;
        float invd2 = fast_rcp(dr * dr + di * di);
        float cr2 = 2.0f * dr * invd2, ci2 = -2.0f * di * invd2;
        float wr2 = 1.0f + k11x[j], wi2 = k11y[j];
        float w2inv = fast_rcp(fmaf(wr2, wr2, wi2 * wi2));
        float vr = wr2 * w2inv, vi = -wi2 * w2inv;
        float t1x = k01x[j] * k10x[j] - k01y[j] * k10y[j];
        float t1y = k01x[j] * k10y[j] + k01y[j] * k10x[j];
        float t2x = t1x * vr - t1y * vi, t2y = t1x * vi + t1y * vr;
        float ex = k00x[j] - t2x, ey = k00y[j] - t2y;
        at_roots[((size_t)layer * Hdim + h) * Lseq + l] =
            make_float2(cr2 * ex - ci2 * ey, cr2 * ey + ci2 * ex);
    }
}

// ---------------- kfft + encoder merged ----------------
// kfft: blocks [0,512); encoder: blocks [512,1536).
// Kd4 layout: [layer][h][2048] float4. Even slot pe: (K[f],K[f+2048]), f=rev11(pe);
// odd slot pe+1: partner (K[g],K[g+2048]), g=2048-f; slot 1: f=1024 self-pair.
__global__ __launch_bounds__(256) void kfft_enc_kernel(const float2* __restrict__ at_roots,
                                                       float4* __restrict__ Kd4,
                                                       const float2* __restrict__ tw,
                                                       const float* __restrict__ x,
                                                       const float* __restrict__ enc_w,
                                                       const float* __restrict__ enc_b,
                                                       const float* __restrict__ nw,
                                                       const float* __restrict__ nb,
                                                       float* __restrict__ h,
                                                       float* __restrict__ hnT) {
    __shared__ __align__(16) float smem[11712];
    int bid = blockIdx.x, t = threadIdx.x;
    if (bid < 512) {
        int hh = bid & 127, layer = bid >> 7;
        float2* data = (float2*)smem;
        float* ktmp = smem + 8192;
        const float2* src = at_roots + ((size_t)layer * Hdim + hh) * Lseq;
#pragma unroll
        for (int k = 0; k < 8; k++) {
            int l = t + 256 * k;
            data[sw(l)] = src[l];
        }
        __syncthreads();
        if (t < 128) {
            float2 v[16];
#pragma unroll
            for (int k = 0; k < 16; k++) v[k] = data[sw(t + 128 * k)];
            fft16_dif<true>(v);
#pragma unroll
            for (int i = 1; i < 16; i++) v[i] = cmulc(v[i], twget(tw, 2 * t * BR4[i]));
#pragma unroll
            for (int i = 0; i < 16; i++) data[sw(i * 128 + t)] = v[i];
        }
        __syncthreads();
        if (t < 128) {
            int i2 = t >> 3, j0 = t & 7;
            int base2 = i2 * 128 + j0;
            float2 v[16];
#pragma unroll
            for (int k = 0; k < 16; k++) v[k] = data[sw(base2 + 8 * k)];
            fft16_dif<true>(v);
#pragma unroll
            for (int i = 1; i < 16; i++) v[i] = cmulc(v[i], twget(tw, 32 * j0 * BR4[i]));
#pragma unroll
            for (int i = 0; i < 16; i++) data[sw(base2 + 8 * i)] = v[i];
        }
        __syncthreads();
        {
            float2 v8[8];
#pragma unroll
            for (int k = 0; k < 8; k++) v8[k] = data[sw(t * 8 + k)];
            fft8_dif<true>(v8);
            int r = BR4[t >> 4], s = BR4[t & 15];
#pragma unroll
            for (int i = 0; i < 8; i++) {
                int l = r + 16 * s + 256 * BR3[i];
                ktmp[l] = v8[i].x * (1.0f / 2048.0f);
            }
        }
        __syncthreads();
        {
            float2 vin[8];
#pragma unroll
            for (int k = 0; k < 8; k++) vin[k] = make_float2(ktmp[t + 256 * k], 0.f);
            fft4096_passA_hz(data, tw, t, vin);
        }
        fft4096_fwd_BC(data, tw, t);
        // paired store (R10-verified): K[f] lives at 12-bit slot 2*rev11(f).
        float4* dst = Kd4 + ((size_t)layer * Hdim + hh) * 2048;
#pragma unroll
        for (int k = 0; k < 4; k++) {
            int pe = 2 * (t + 256 * k);  // even, < 2048
            float2 a = data[sw(2 * pe)], bb = data[sw(2 * pe + 1)];
            dst[pe] = make_float4(a.x, a.y, bb.x, bb.y);
            int f = __brev((unsigned)pe) >> 21;
            int g = (2048 - f) & 2047;
            int pm = __brev((unsigned)g) >> 21;
            int srcp = (pe == 0) ? 1 : pm;  // slot1 = f=1024 pair
            float2 c = data[sw(2 * srcp)], d = data[sw(2 * srcp + 1)];
            dst[pe + 1] = make_float4(c.x, c.y, d.x, d.y);
        }
    } else {
        // ---- encoder + fused LN ----
        int r0 = (bid - 512) * 16;
        float* ws = smem;
        float* xst = smem + 8320;
        float* dots = smem + 9600;
        float2* mv = (float2*)(smem + 11648);
        for (int i = t; i < 128 * 64; i += 256) ws[(i >> 6) * 65 + (i & 63)] = enc_w[i];
        for (int i = t; i < 16 * 64; i += 256) {
            int r = i >> 6, k = i & 63;
            xst[k * 20 + r] = x[(size_t)(r0 + r) * 64 + k];
        }
        __syncthreads();
        int o = t & 127, half = t >> 7;
        float acc[8];
        float bo = enc_b[o];
#pragma unroll
        for (int j = 0; j < 8; j++) acc[j] = bo;
        for (int k = 0; k < 64; k++) {
            float wv = ws[o * 65 + k];
            float4 xa = *(const float4*)&xst[k * 20 + half * 8];
            float4 xb = *(const float4*)&xst[k * 20 + half * 8 + 4];
            acc[0] += wv * xa.x; acc[1] += wv * xa.y; acc[2] += wv * xa.z; acc[3] += wv * xa.w;
            acc[4] += wv * xb.x; acc[5] += wv * xb.y; acc[6] += wv * xb.z; acc[7] += wv * xb.w;
        }
#pragma unroll
        for (int j = 0; j < 8; j++) dots[(half * 8 + j) * 128 + o] = acc[j];
        __syncthreads();
        {
            int row = t >> 4, lane = t & 15;
            float s1 = 0.f, s2 = 0.f;
#pragma unroll
            for (int i = 0; i < 8; i++) {
                float v = dots[row * 128 + lane * 8 + i];
                s1 += v; s2 += v * v;
            }
#pragma unroll
            for (int m = 1; m < 16; m <<= 1) { s1 += __shfl_xor(s1, m); s2 += __shfl_xor(s2, m); }
            if (lane == 0) {
                float mu = s1 * (1.0f / 128.0f);
                float var = s2 * (1.0f / 128.0f) - mu * mu;
                mv[row] = make_float2(mu, fast_rsq(var + 1e-5f));
            }
        }
        __syncthreads();
        int c = t & 127;
        int bb = r0 >> 11, l0 = r0 & 2047;
        float nwc = nw[c], nbc = nb[c];
        float hnv[8];
#pragma unroll
        for (int j = 0; j < 8; j++) {
            int r = half * 8 + j;
            float v = dots[r * 128 + c];
            h[(size_t)(r0 + r) * Hdim + c] = v;
            float2 m = mv[r];
            hnv[j] = (v - m.x) * m.y * nwc + nbc;
        }
        float* dst = hnT + ((size_t)bb * Hdim + c) * Lseq + l0 + half * 8;
        *(float4*)dst = make_float4(hnv[0], hnv[1], hnv[2], hnv[3]);
        *(float4*)(dst + 4) = make_float4(hnv[4], hnv[5], hnv[6], hnv[7]);
    }
}

// ---------------- FFT convolution: half-size complex, radices (8,8,8,4), 1 ch/block ----
// z[n] = u[2n] + i*u[2n+1] (n<1024, rest zero); 2048-pt FFT; untangle+pointwise;
// inverse; y[2n],y[2n+1] from z'[n], n<1024. All 256 threads active every pass.
__global__ __launch_bounds__(256) void conv_kernel(float* __restrict__ hnT,
                                                   const float4* __restrict__ Kd4,
                                                   const float* __restrict__ dvec,
                                                   const float2* __restrict__ tw) {
    int h = blockIdx.x, b = blockIdx.y, t = threadIdx.x;
    __shared__ float2 data[2176];  // ph-padded 2048
    float* u0 = hnT + ((size_t)b * Hdim + h) * Lseq;
    float2 zreg[4];
    {   // fwd pass A: radix-8 stride 256, inputs i>=4 are zero -> degenerate 1st stage
        float2 v[8];
#pragma unroll
        for (int k = 0; k < 4; k++) {
            int n = t + 256 * k;
            v[k] = *(const float2*)(u0 + 2 * n);
            zreg[k] = v[k];
        }
#pragma unroll
        for (int j = 0; j < 4; j++)
            v[j + 4] = cmulf(v[j], make_float2(W16R[2 * j], W16I[2 * j]));  // W8^j
#pragma unroll
        for (int mi = 1; mi < 3; mi++) {
            const int m = 4 >> mi;
#pragma unroll
            for (int g = 0; g < 8; g += 2 * m) {
#pragma unroll
                for (int j = 0; j < m; j++) {
                    float wr = W16R[j << (mi + 1)], wi = W16I[j << (mi + 1)];
                    float2 a = v[g + j], bb = v[g + j + m];
                    float dx = a.x - bb.x, dy = a.y - bb.y;
                    v[g + j] = make_float2(a.x + bb.x, a.y + bb.y);
                    v[g + j + m] = make_float2(dx * wr - dy * wi, dx * wi + dy * wr);
                }
            }
        }
#pragma unroll
        for (int i = 1; i < 8; i++) v[i] = cmulf(v[i], twget(tw, 2 * t * BR3[i]));
#pragma unroll
        for (int i = 0; i < 8; i++) data[ph(t + 256 * i)] = v[i];
    }
    __syncthreads();
    {   // fwd pass B: radix-8 stride 32
        int j = t & 31;
        int base = (t >> 5) * 256 + j;
        float2 v[8];
#pragma unroll
        for (int i = 0; i < 8; i++) v[i] = data[ph(base + 32 * i)];
        fft8_dif<false>(v);
#pragma unroll
        for (int i = 1; i < 8; i++) v[i] = cmulf(v[i], twget(tw, 16 * j * BR3[i]));
#pragma unroll
        for (int i = 0; i < 8; i++) data[ph(base + 32 * i)] = v[i];
    }
    __syncthreads();
    {   // fwd pass C: radix-8 stride 4
        int j = t & 3;
        int base = (t >> 2) * 32 + j;
        float2 v[8];
#pragma unroll
        for (int i = 0; i < 8; i++) v[i] = data[ph(base + 4 * i)];
        fft8_dif<false>(v);
#pragma unroll
        for (int i = 1; i < 8; i++) v[i] = cmulf(v[i], twget(tw, 128 * j * BR3[i]));
#pragma unroll
        for (int i = 0; i < 8; i++) data[ph(base + 4 * i)] = v[i];
    }
    __syncthreads();
    {   // fwd pass D: radix-4 stride 1 (no twiddle), 2 groups/thread
#pragma unroll
        for (int g = 0; g < 2; g++) {
            int base = 8 * t + 4 * g;
            float2 v[4];
#pragma unroll
            for (int i = 0; i < 4; i++) v[i] = data[ph(base + i)];
            fft4_dif(v);
#pragma unroll
            for (int i = 0; i < 4; i++) data[ph(base + i)] = v[i];
        }
    }
    __syncthreads();
    // untangle (f, 2048-f) + pointwise (R10-verified), 11-bit bit-reversed slots.
    const float4* Kp = Kd4 + (size_t)h * 2048;
    const float hs = 0.5f / 2048.0f;  // 0.5 untangle * 1/2048 unnormalized ifft
    float dcoef = dvec[h];
#pragma unroll
    for (int k = 0; k < 4; k++) {
        int idx = t + 256 * k;          // < 1024
        int p = 2 * idx;                // f = rev11(p) in [0,1024)
        int f = __brev((unsigned)p) >> 21;
        int g = (2048 - f) & 2047;
        int pm = __brev((unsigned)g) >> 21;
        float2 Zf = data[ph(p)], Zg = data[ph(pm)];
        float2 W = tw[f];               // W4096^f ... NOTE: need W_4096^f for untangle
        float2 Eu = make_float2(0.5f * (Zf.x + Zg.x), 0.5f * (Zf.y - Zg.y));
        float2 Ou = make_float2(0.5f * (Zf.y + Zg.y), -0.5f * (Zf.x - Zg.x));
        float2 T = cmulf(W, Ou);
        float2 Uf  = make_float2(Eu.x + T.x, Eu.y + T.y);   // U[f]
        float2 Uf2 = make_float2(Eu.x - T.x, Eu.y - T.y);   // U[f+2048]
        float4 Kf = Kp[p];
        float2 Xf  = cmulf(Uf,  make_float2(Kf.x, Kf.y));
        float2 Xf2 = cmulf(Uf2, make_float2(Kf.z, Kf.w));
        float2 Ep = make_float2((Xf.x + Xf2.x) * hs, (Xf.y + Xf2.y) * hs);
        float2 Dp = make_float2((Xf.x - Xf2.x) * hs, (Xf.y - Xf2.y) * hs);
        float2 Op = cmulc(Dp, W);
        data[ph(p)] = make_float2(Ep.x - Op.y, Ep.y + Op.x);
        if (pm != p) {
            float2 Ug  = make_float2(Uf2.x, -Uf2.y);
            float2 Ug2 = make_float2(Uf.x,  -Uf.y);
            float4 Kg = Kp[p + 1];
            float2 Xg  = cmulf(Ug,  make_float2(Kg.x, Kg.y));
            float2 Xg2 = cmulf(Ug2, make_float2(Kg.z, Kg.w));
            float2 Eg = make_float2((Xg.x + Xg2.x) * hs, (Xg.y + Xg2.y) * hs);
            float2 Dg = make_float2((Xg.x - Xg2.x) * hs, (Xg.y - Xg2.y) * hs);
            float2 Og = cmulf(W, Dg);
            Og = make_float2(-Og.x, -Og.y);
            data[ph(pm)] = make_float2(Eg.x - Og.y, Eg.y + Og.x);
        }
    }
    if (t == 0) {  // f = 1024 self-pair at slot 1; W = tw[1024] = (0,-1)
        float2 Z = data[ph(1)];
        float2 W = make_float2(0.f, -1.f);
        float2 Eu = make_float2(Z.x, 0.f);
        float2 Ou = make_float2(Z.y, 0.f);
        float2 T = cmulf(W, Ou);
        float2 Uf = make_float2(Eu.x + T.x, Eu.y + T.y);
        float2 Uf2 = make_float2(Eu.x - T.x, Eu.y - T.y);
        float4 Kf = Kp[1];
        float2 Xf = cmulf(Uf, make_float2(Kf.x, Kf.y));
        float2 Xf2 = cmulf(Uf2, make_float2(Kf.z, Kf.w));
        float2 Ep = make_float2((Xf.x + Xf2.x) * hs, (Xf.y + Xf2.y) * hs);
        float2 Dp = make_float2((Xf.x - Xf2.x) * hs, (Xf.y - Xf2.y) * hs);
        float2 Op = cmulc(Dp, W);
        data[ph(1)] = make_float2(Ep.x - Op.y, Ep.y + Op.x);
    }
    __syncthreads();
    {   // inv pass D': radix-4 stride 1
#pragma unroll
        for (int g = 0; g < 2; g++) {
            int base = 8 * t + 4 * g;
            float2 v[4];
#pragma unroll
            for (int i = 0; i < 4; i++) v[i] = data[ph(base + i)];
            fft4_dit(v);
#pragma unroll
            for (int i = 0; i < 4; i++) data[ph(base + i)] = v[i];
        }
    }
    __syncthreads();
    {   // inv pass C': radix-8 stride 4 (pre-conj-twiddle)
        int j = t & 3;
        int base = (t >> 2) * 32 + j;
        float2 v[8];
        v[0] = data[ph(base)];
#pragma unroll
        for (int i = 1; i < 8; i++)
            v[i] = cmulc(data[ph(base + 4 * i)], twget(tw, 128 * j * BR3[i]));
        fft8_dit<true>(v);
#pragma unroll
        for (int i = 0; i < 8; i++) data[ph(base + 4 * i)] = v[i];
    }
    __syncthreads();
    {   // inv pass B': radix-8 stride 32
        int j = t & 31;
        int base = (t >> 5) * 256 + j;
        float2 v[8];
        v[0] = data[ph(base)];
#pragma unroll
        for (int i = 1; i < 8; i++)
            v[i] = cmulc(data[ph(base + 32 * i)], twget(tw, 16 * j * BR3[i]));
        fft8_dit<true>(v);
#pragma unroll
        for (int i = 0; i < 8; i++) data[ph(base + 32 * i)] = v[i];
    }
    __syncthreads();
    {   // inv pass A': radix-8 stride 256, final stage pruned to outputs n<1024
        float2 v[8];
        v[0] = data[ph(t)];
#pragma unroll
        for (int i = 1; i < 8; i++)
            v[i] = cmulc(data[ph(t + 256 * i)], twget(tw, 2 * t * BR3[i]));
        // DIT stages mi=2 (m=1), mi=1 (m=2) full:
#pragma unroll
        for (int mi = 2; mi >= 1; mi--) {
            const int m = 4 >> mi;
#pragma unroll
            for (int g = 0; g < 8; g += 2 * m) {
#pragma unroll
                for (int j = 0; j < m; j++) {
                    float wr = W16R[j << (mi + 1)], wi = -W16I[j << (mi + 1)];
                    float2 a = v[g + j], bb = v[g + j + m];
                    float bx = bb.x * wr - bb.y * wi, by = bb.x * wi + bb.y * wr;
                    v[g + j] = make_float2(a.x + bx, a.y + by);
                    v[g + j + m] = make_float2(a.x - bx, a.y - by);
                }
            }
        }
        // final stage m=4: sums only (outputs n = t+256j, j<4)
#pragma unroll
        for (int j = 0; j < 4; j++) {
            float wr = W16R[2 * j], wi = -W16I[2 * j];
            float2 bb = v[j + 4];
            float bx = bb.x * wr - bb.y * wi, by = bb.x * wi + bb.y * wr;
            v[j] = make_float2(v[j].x + bx, v[j].y + by);
        }
#pragma unroll
        for (int k = 0; k < 4; k++) {
            int n = t + 256 * k;
            float y0 = gelu_f(v[k].x + zreg[k].x * dcoef);
            float y1 = gelu_f(v[k].y + zreg[k].y * dcoef);
            *(float2*)(u0 + 2 * n) = make_float2(y0, y1);
        }
    }
}

// ---------------- gated MLP via bf16 MFMA + residual + fused LN: 32 rows/block ----------------
__global__ __launch_bounds__(256) void mlp_kernel(const float* __restrict__ yT,
                                                  float* __restrict__ h,
                                                  float* __restrict__ hnT,
                                                  const __bf16* __restrict__ w1b,
                                                  const __bf16* __restrict__ w2b,
                                                  const float* __restrict__ b1,
                                                  const float* __restrict__ b2,
                                                  const float* __restrict__ nw,
                                                  const float* __restrict__ nb,
                                                  int do_ln) {
    int r0 = blockIdx.x * 32;
    int t = threadIdx.x;
    int wave = t >> 6, lane = t & 63;
    __shared__ __align__(16) __bf16 ybf[32 * 136];
    __shared__ float dots[32 * 132];
    __shared__ float2 mv[32];
    int bb = r0 >> 11, l0 = r0 & 2047;
    for (int i = t; i < 32 * 128; i += 256) {
        int r = i & 31, k = i >> 5;
        ybf[r * 136 + k] = (__bf16)yT[((size_t)bb * Hdim + k) * Lseq + l0 + r];
    }
    __syncthreads();
    int m = lane & 31, half = lane >> 5;
    bf16x8 a[8];
#pragma unroll
    for (int kk = 0; kk < 8; kk++)
        a[kk] = *(const bf16x8*)&ybf[m * 136 + kk * 16 + half * 8];
    int out = 32 * wave + m;
    const __bf16* w1r = w1b + (size_t)out * 128 + half * 8;
    const __bf16* w2r = w2b + (size_t)out * 128 + half * 8;
    f32x16 acc1, acc2;
#pragma unroll
    for (int i = 0; i < 16; i++) { acc1[i] = 0.f; acc2[i] = 0.f; }
#pragma unroll
    for (int kk = 0; kk < 8; kk++) {
        bf16x8 bw1 = *(const bf16x8*)(w1r + kk * 16);
        bf16x8 bw2 = *(const bf16x8*)(w2r + kk * 16);
        acc1 = __builtin_amdgcn_mfma_f32_32x32x16_bf16(a[kk], bw1, acc1, 0, 0, 0);
        acc2 = __builtin_amdgcn_mfma_f32_32x32x16_bf16(a[kk], bw2, acc2, 0, 0, 0);
    }
    float bias1 = b1[out], bias2 = b2[out];
#pragma unroll
    for (int reg = 0; reg < 16; reg++) {
        int row = (reg & 3) + 8 * (reg >> 2) + 4 * half;
        float v1 = acc1[reg] + bias1;
        float v2 = acc2[reg] + bias2;
        float g = fast_rcp(1.0f + __expf(-v2));
        float hv = h[(size_t)(r0 + row) * Hdim + out] + v1 * g;
        dots[row * 132 + out] = hv;
    }
    __syncthreads();
    if (do_ln) {
        int row = t >> 3, lane8 = t & 7;
        float s1 = 0.f, s2 = 0.f;
        int base = row * 132 + lane8 * 16;
#pragma unroll
        for (int q = 0; q < 4; q++) {
            float4 v4 = *(const float4*)&dots[base + 4 * q];
            s1 += v4.x + v4.y + v4.z + v4.w;
            s2 += v4.x * v4.x + v4.y * v4.y + v4.z * v4.z + v4.w * v4.w;
        }
#pragma unroll
        for (int mm = 1; mm < 8; mm <<= 1) { s1 += __shfl_xor(s1, mm); s2 += __shfl_xor(s2, mm); }
        if (lane8 == 0) {
            float mu = s1 * (1.0f / 128.0f);
            float var = s2 * (1.0f / 128.0f) - mu * mu;
            mv[row] = make_float2(mu, fast_rsq(var + 1e-5f));
        }
        __syncthreads();
        int o = t & 127, rh = t >> 7;
        float nwc = nw[o], nbc = nb[o];
        float hnv[16];
#pragma unroll
        for (int j = 0; j < 16; j++) {
            int r = rh * 16 + j;
            float hvv = dots[r * 132 + o];
            h[(size_t)(r0 + r) * Hdim + o] = hvv;
            float2 mvv = mv[r];
            hnv[j] = (hvv - mvv.x) * mvv.y * nwc + nbc;
        }
        float* dst = hnT + ((size_t)bb * Hdim + o) * Lseq + l0 + rh * 16;
        *(float4*)(dst)      = make_float4(hnv[0],  hnv[1],  hnv[2],  hnv[3]);
        *(float4*)(dst + 4)  = make_float4(hnv[4],  hnv[5],  hnv[6],  hnv[7]);
        *(float4*)(dst + 8)  = make_float4(hnv[8],  hnv[9],  hnv[10], hnv[11]);
        *(float4*)(dst + 12) = make_float4(hnv[12], hnv[13], hnv[14], hnv[15]);
    } else {
        int o = t & 127, rh = t >> 7;
#pragma unroll
        for (int j = 0; j < 16; j++) {
            int r = rh * 16 + j;
            h[(size_t)(r0 + r) * Hdim + o] = dots[r * 132 + o];
        }
    }
}

// ---------------- decoder: 32 rows/block ----------------
__global__ __launch_bounds__(256) void decoder_kernel(const float* __restrict__ h,
                                                      const float* __restrict__ w,
                                                      const float* __restrict__ b,
                                                      float* __restrict__ out) {
    int r0 = blockIdx.x * 32;
    int t = threadIdx.x;
    __shared__ float ws[64 * 129];
    __shared__ __align__(16) float hst[128 * 36];
    for (int i = t; i < 64 * 128; i += 256) ws[(i >> 7) * 129 + (i & 127)] = w[i];
    for (int i = t; i < 32 * 128; i += 256) {
        int r = i >> 7, k = i & 127;
        hst[k * 36 + r] = h[(size_t)(r0 + r) * Hdim + k];
    }
    __syncthreads();
    int o = t & 63, q = t >> 6;
    float acc[8];
    float bo = b[o];
#pragma unroll
    for (int j = 0; j < 8; j++) acc[j] = bo;
    for (int k = 0; k < 128; k++) {
        float wv = ws[o * 129 + k];
        float4 ha = *(const float4*)&hst[k * 36 + q * 8];
        float4 hb = *(const float4*)&hst[k * 36 + q * 8 + 4];
        acc[0] += wv * ha.x; acc[1] += wv * ha.y; acc[2] += wv * ha.z; acc[3] += wv * ha.w;
        acc[4] += wv * hb.x; acc[5] += wv * hb.y; acc[6] += wv * hb.z; acc[7] += wv * hb.w;
    }
#pragma unroll
    for (int j = 0; j < 8; j++) out[(size_t)(r0 + q * 8 + j) * 64 + o] = acc[j];
}

extern "C" void kernel_launch(void* const* d_in, const int* in_sizes, int n_in,
                              void* d_out, int out_size, void* d_ws, size_t ws_size,
                              hipStream_t stream) {
    const float* x      = (const float*)d_in[0];
    const float* enc_w  = (const float*)d_in[2];
    const float* enc_b  = (const float*)d_in[3];
    const float* dec_w  = (const float*)d_in[4];
    const float* dec_b  = (const float*)d_in[5];
    const float* lam_re = (const float*)d_in[6];
    const float* lam_im = (const float*)d_in[7];
    const float* p_re   = (const float*)d_in[8];
    const float* p_im   = (const float*)d_in[9];
    const float* b_re   = (const float*)d_in[10];
    const float* b_im   = (const float*)d_in[11];
    const float* c_re   = (const float*)d_in[12];
    const float* c_im   = (const float*)d_in[13];
    const float* dvec   = (const float*)d_in[14];
    const float* lstep  = (const float*)d_in[15];
    const float* norm_w = (const float*)d_in[16];
    const float* norm_b = (const float*)d_in[17];
    const float* w1     = (const float*)d_in[18];
    const float* b1     = (const float*)d_in[19];
    const float* w2     = (const float*)d_in[20];
    const float* b2     = (const float*)d_in[21];
    float* out = (float*)d_out;

    char* ws = (char*)d_ws;
    float2* tw  = (float2*)ws;  ws += 2048 * sizeof(float2);
    float*  h   = (float*)ws;   ws += (size_t)Bsz * Lseq * Hdim * sizeof(float);
    float*  hnT = (float*)ws;   ws += (size_t)Bsz * Lseq * Hdim * sizeof(float);
    float2* atr = (float2*)ws;  ws += (size_t)NLAYERS * Hdim * Lseq * sizeof(float2);
    float4* Kd4 = (float4*)ws;  ws += (size_t)NLAYERS * Hdim * 2048 * sizeof(float4);
    __bf16* wbf = (__bf16*)ws;  ws += (size_t)NLAYERS * 2 * Hdim * Hdim * sizeof(__bf16);

    const int nrows = Bsz * Lseq;  // 16384

    prep_kernel<<<8 + 256 + 2048, 256, 0, stream>>>(
        lam_re, lam_im, p_re, p_im, b_re, b_im, c_re, c_im, lstep, w1, w2, tw, wbf, atr);
    kfft_enc_kernel<<<512 + nrows / 16, 256, 0, stream>>>(
        atr, Kd4, tw, x, enc_w, enc_b, norm_w, norm_b, h, hnT);
    for (int L = 0; L < NLAYERS; L++) {
        conv_kernel<<<dim3(Hdim, Bsz), 256, 0, stream>>>(
            hnT, Kd4 + (size_t)L * Hdim * 2048, dvec + L * Hdim, tw);
        int do_ln = (L < NLAYERS - 1) ? 1 : 0;
        const float* nwn = norm_w + ((L + 1) % NLAYERS) * Hdim;
        const float* nbn = norm_b + ((L + 1) % NLAYERS) * Hdim;
        const __bf16* w1bL = wbf + (size_t)L * 2 * Hdim * Hdim;
        const __bf16* w2bL = w1bL + Hdim * Hdim;
        mlp_kernel<<<nrows / 32, 256, 0, stream>>>(hnT, h, hnT, w1bL, w2bL,
                                                   b1 + L * Hdim, b2 + L * Hdim,
                                                   nwn, nbn, do_ln);
    }
    decoder_kernel<<<nrows / 32, 256, 0, stream>>>(h, dec_w, dec_b, out);
}

// Round 15
// 310.291 us; speedup vs baseline: 1.0315x; 1.0315x over previous
//
#include <hip/hip_runtime.h>
#include <hip/hip_bf16.h>

// S4 (DPLR) forward, B=8 L=2048 IN=OUT=64 H=128 N=64, 4 layers.
// R15: conv reverted to R13's 6-pass radix-16^3 FFT (fastest of 4 variants;
// conv is barrier/pass-count bound) + BATCH-PAIR complex packing: z=u_b0+i*u_b1
// with the SAME real kernel K -> by linearity y_b0=Re, y_b1=Im. Eliminates the
// entire untangle: pointwise = one coalesced float2 Kd load + one cmul per bin.
// kfft stores plain slot-order spectrum. prep/mlp/decoder = R13.

#define Bsz 8
#define Lseq 2048
#define Hdim 128
#define Npol 64
#define NLAYERS 4

typedef __bf16 bf16x8 __attribute__((ext_vector_type(8)));
typedef float f32x16 __attribute__((ext_vector_type(16)));

__device__ __forceinline__ float fast_rcp(float x) { return __builtin_amdgcn_rcpf(x); }
__device__ __forceinline__ float fast_rsq(float x) { return __builtin_amdgcn_rsqf(x); }

__device__ __forceinline__ float2 cmulf(float2 a, float2 b) {
    return make_float2(a.x * b.x - a.y * b.y, a.x * b.y + a.y * b.x);
}
__device__ __forceinline__ float2 cmulc(float2 a, float2 b) {  // a * conj(b)
    return make_float2(a.x * b.x + a.y * b.y, a.y * b.x - a.x * b.y);
}

__device__ __forceinline__ float gelu_f(float v) {
    float z = 0.7978845608028654f * (v + 0.044715f * v * v * v);
    float e = __expf(2.0f * z);
    return v - v * fast_rcp(e + 1.0f);
}

// XOR swizzle: strides 1/16/256 all conflict-uniform for the 4096 arrays.
__device__ __forceinline__ int sw(int i) { return (i & ~15) | ((i ^ (i >> 4)) & 15); }

static __device__ const float W16R[8] = {1.f, 0.9238795325f, 0.7071067812f, 0.3826834324f,
                                         0.f, -0.3826834324f, -0.7071067812f, -0.9238795325f};
static __device__ const float W16I[8] = {0.f, -0.3826834324f, -0.7071067812f, -0.9238795325f,
                                         -1.f, -0.9238795325f, -0.7071067812f, -0.3826834324f};
static __device__ const int BR4[16] = {0, 8, 4, 12, 2, 10, 6, 14, 1, 9, 5, 13, 3, 11, 7, 15};
static __device__ const int BR3[8] = {0, 4, 2, 6, 1, 5, 3, 7};

__device__ __forceinline__ float2 twget(const float2* __restrict__ tw, int e) {
    float2 w = tw[e & 2047];
    if (e & 2048) { w.x = -w.x; w.y = -w.y; }
    return w;
}

template <bool INV>
__device__ __forceinline__ void fft16_dif(float2 v[16]) {
#pragma unroll
    for (int mi = 0; mi < 4; mi++) {
        const int m = 8 >> mi;
#pragma unroll
        for (int g = 0; g < 16; g += 2 * m) {
#pragma unroll
            for (int j = 0; j < m; j++) {
                float wr = W16R[j << mi];
                float wi = INV ? -W16I[j << mi] : W16I[j << mi];
                float2 a = v[g + j], b = v[g + j + m];
                float dx = a.x - b.x, dy = a.y - b.y;
                v[g + j] = make_float2(a.x + b.x, a.y + b.y);
                v[g + j + m] = make_float2(dx * wr - dy * wi, dx * wi + dy * wr);
            }
        }
    }
}

template <bool INV>
__device__ __forceinline__ void fft16_dit(float2 v[16]) {
#pragma unroll
    for (int mi = 3; mi >= 0; mi--) {
        const int m = 8 >> mi;
#pragma unroll
        for (int g = 0; g < 16; g += 2 * m) {
#pragma unroll
            for (int j = 0; j < m; j++) {
                float wr = W16R[j << mi];
                float wi = INV ? -W16I[j << mi] : W16I[j << mi];
                float2 a = v[g + j], b = v[g + j + m];
                float bx = b.x * wr - b.y * wi, by = b.x * wi + b.y * wr;
                v[g + j] = make_float2(a.x + bx, a.y + by);
                v[g + j + m] = make_float2(a.x - bx, a.y - by);
            }
        }
    }
}

template <bool INV>
__device__ __forceinline__ void fft8_dif(float2 v[8]) {
#pragma unroll
    for (int mi = 0; mi < 3; mi++) {
        const int m = 4 >> mi;
#pragma unroll
        for (int g = 0; g < 8; g += 2 * m) {
#pragma unroll
            for (int j = 0; j < m; j++) {
                float wr = W16R[j << (mi + 1)];
                float wi = INV ? -W16I[j << (mi + 1)] : W16I[j << (mi + 1)];
                float2 a = v[g + j], b = v[g + j + m];
                float dx = a.x - b.x, dy = a.y - b.y;
                v[g + j] = make_float2(a.x + b.x, a.y + b.y);
                v[g + j + m] = make_float2(dx * wr - dy * wi, dx * wi + dy * wr);
            }
        }
    }
}

// Pass A of the zero-padded (upper half) forward 4096 FFT, input in registers.
// First radix-16 stage degenerates: b-half is zero -> v[j+8] = v[j]*W16(j).
__device__ __forceinline__ void fft4096_passA_hz(float2* data, const float2* __restrict__ tw,
                                                 int t, const float2 vin[8]) {
    float2 v[16];
#pragma unroll
    for (int j = 0; j < 8; j++) v[j] = vin[j];
#pragma unroll
    for (int j = 0; j < 8; j++)
        v[j + 8] = cmulf(v[j], make_float2(W16R[j], W16I[j]));
#pragma unroll
    for (int mi = 1; mi < 4; mi++) {
        const int m = 8 >> mi;
#pragma unroll
        for (int g = 0; g < 16; g += 2 * m) {
#pragma unroll
            for (int j = 0; j < m; j++) {
                float wr = W16R[j << mi], wi = W16I[j << mi];
                float2 a = v[g + j], b = v[g + j + m];
                float dx = a.x - b.x, dy = a.y - b.y;
                v[g + j] = make_float2(a.x + b.x, a.y + b.y);
                v[g + j + m] = make_float2(dx * wr - dy * wi, dx * wi + dy * wr);
            }
        }
    }
#pragma unroll
    for (int i = 1; i < 16; i++) v[i] = cmulf(v[i], twget(tw, t * BR4[i]));
#pragma unroll
    for (int i = 0; i < 16; i++) data[sw(i * 256 + t)] = v[i];
}

// Passes B and C of the forward 4096 FFT (leading barrier included).
__device__ __forceinline__ void fft4096_fwd_BC(float2* data, const float2* __restrict__ tw, int t) {
    __syncthreads();
    {
        int j0 = t & 15;
        int base = (t >> 4) * 256 + j0;
        float2 v[16];
#pragma unroll
        for (int k = 0; k < 16; k++) v[k] = data[sw(base + 16 * k)];
        fft16_dif<false>(v);
#pragma unroll
        for (int i = 1; i < 16; i++) v[i] = cmulf(v[i], twget(tw, 16 * j0 * BR4[i]));
#pragma unroll
        for (int i = 0; i < 16; i++) data[sw(base + 16 * i)] = v[i];
    }
    __syncthreads();
    {
        float2 v[16];
#pragma unroll
        for (int k = 0; k < 16; k++) v[k] = data[sw(t * 16 + k)];
        fft16_dif<false>(v);
#pragma unroll
        for (int i = 0; i < 16; i++) data[sw(t * 16 + i)] = v[i];
    }
    __syncthreads();
}

// ---------------- prep: twiddle + weight-bf16 + spectrum, one launch ----------------
__global__ __launch_bounds__(256, 4) void prep_kernel(const float* __restrict__ lam_re,
                                                      const float* __restrict__ lam_im,
                                                      const float* __restrict__ p_re,
                                                      const float* __restrict__ p_im,
                                                      const float* __restrict__ b_re,
                                                      const float* __restrict__ b_im,
                                                      const float* __restrict__ c_re,
                                                      const float* __restrict__ c_im,
                                                      const float* __restrict__ log_step,
                                                      const float* __restrict__ w1,
                                                      const float* __restrict__ w2,
                                                      float2* __restrict__ tw,
                                                      __bf16* __restrict__ wbf,
                                                      float2* __restrict__ at_roots) {
    int bid = blockIdx.x, t = threadIdx.x;
    if (bid < 8) {
        int k = bid * 256 + t;
        if (k < 2048) {
            double a = -6.283185307179586476925286766559 * (double)k / 4096.0;
            tw[k] = make_float2((float)cos(a), (float)sin(a));
        }
        return;
    }
    if (bid < 264) {
        int i = (bid - 8) * 256 + t;
        int layer = i >> 14, rem = i & 16383;
        wbf[((size_t)layer * 2) * 16384 + rem] = (__bf16)w1[i];
        wbf[((size_t)layer * 2 + 1) * 16384 + rem] = (__bf16)w2[i];
        return;
    }
    int s = bid - 264;
    int h = s & 127, layer = (s >> 7) & 3;
    int l0 = 512 * (s >> 9);
    __shared__ __align__(16) float4 polA[Npol];
    __shared__ __align__(16) float4 polB[Npol];
    __shared__ float n11S[Npol];
    int baseP = (layer * Hdim + h) * Npol;
    if (t < Npol) {
        int n = t;
        float lr = lam_re[baseP + n], li = lam_im[baseP + n];
        float pr = p_re[baseP + n], pi = p_im[baseP + n];
        float br = b_re[baseP + n], bi = b_im[baseP + n];
        float cr = c_re[baseP + n], ci = c_im[baseP + n];
        polA[n] = make_float4(lr, li, cr * br + ci * bi, cr * bi - ci * br);
        polB[n] = make_float4(cr * pr + ci * pi, cr * pi - ci * pr,
                              pr * br + pi * bi, pr * bi - pi * br);
        n11S[n] = pr * pr + pi * pi;
    }
    __syncthreads();
    float step = expf(log_step[layer * Hdim + h]);
    float gs = 2.0f / step;

    float gr[2], gi[2];
#pragma unroll
    for (int j = 0; j < 2; j++) {
        int l = l0 + t + 256 * j;
        float ang = -6.283185307179586f * (float)l / (float)Lseq;
        float wr = cosf(ang), wi = sinf(ang);  // fp32 omega on purpose (range)
        float dr = 1.0f + wr, di = wi;
        float invd2 = fast_rcp(dr * dr + di * di);
        float nr = 1.0f - wr, ni = -wi;
        gr[j] = gs * (nr * dr + ni * di) * invd2;
        gi[j] = gs * (ni * dr - nr * di) * invd2;
    }
    float k00x[2] = {0, 0}, k00y[2] = {0, 0};
    float k01x[2] = {0, 0}, k01y[2] = {0, 0};
    float k10x[2] = {0, 0}, k10y[2] = {0, 0};
    float k11x[2] = {0, 0}, k11y[2] = {0, 0};
#pragma unroll 4
    for (int n = 0; n < Npol; n++) {
        float4 A = polA[n];
        float4 B = polB[n];
        float n11 = n11S[n];
#pragma unroll
        for (int j = 0; j < 2; j++) {
            float er = gr[j] - A.x, ei = gi[j] - A.y;
            float inv2 = fast_rcp(fmaf(er, er, ei * ei));
            float ir = er * inv2;
            float mi = ei * inv2;
            k00x[j] = fmaf(A.z, ir, fmaf(A.w, mi, k00x[j]));
            k00y[j] = fmaf(A.w, ir, fmaf(-A.z, mi, k00y[j]));
            k01x[j] = fmaf(B.x, ir, fmaf(B.y, mi, k01x[j]));
            k01y[j] = fmaf(B.y, ir, fmaf(-B.x, mi, k01y[j]));
            k10x[j] = fmaf(B.z, ir, fmaf(B.w, mi, k10x[j]));
            k10y[j] = fmaf(B.w, ir, fmaf(-B.z, mi, k10y[j]));
            k11x[j] = fmaf(n11, ir, k11x[j]);
            k11y[j] = fmaf(-n11, mi, k11y[j]);
        }
    }
#pragma unroll
    for (int j = 0; j < 2; j++) {
        int l = l0 + t + 256 * j;
        float ang = -6.283185307179586f * (float)l / (float)Lseq;
        float wr = cosf(ang), wi = sinf(ang);
        float dr = 1.0f + wr, di = wi;
        float invd2 = fast_rcp(dr * dr + di * di);
        float cr2 = 2.0f * dr * invd2, ci2 = -2.0f * di * invd2;
        float wr2 = 1.0f + k11x[j], wi2 = k11y[j];
        float w2inv = fast_rcp(fmaf(wr2, wr2, wi2 * wi2));
        float vr = wr2 * w2inv, vi = -wi2 * w2inv;
        float t1x = k01x[j] * k10x[j] - k01y[j] * k10y[j];
        float t1y = k01x[j] * k10y[j] + k01y[j] * k10x[j];
        float t2x = t1x * vr - t1y * vi, t2y = t1x * vi + t1y * vr;
        float ex = k00x[j] - t2x, ey = k00y[j] - t2y;
        at_roots[((size_t)layer * Hdim + h) * Lseq + l] =
            make_float2(cr2 * ex - ci2 * ey, cr2 * ey + ci2 * ex);
    }
}

// ---------------- kfft + encoder merged ----------------
// kfft: blocks [0,512); encoder: blocks [512,1536).
// Kd1 layout: [layer][h][p] float2 = FFT4096(K_h)[slot p], p bit-reversed.
__global__ __launch_bounds__(256) void kfft_enc_kernel(const float2* __restrict__ at_roots,
                                                       float2* __restrict__ Kd1,
                                                       const float2* __restrict__ tw,
                                                       const float* __restrict__ x,
                                                       const float* __restrict__ enc_w,
                                                       const float* __restrict__ enc_b,
                                                       const float* __restrict__ nw,
                                                       const float* __restrict__ nb,
                                                       float* __restrict__ h,
                                                       float* __restrict__ hnT) {
    __shared__ __align__(16) float smem[11712];
    int bid = blockIdx.x, t = threadIdx.x;
    if (bid < 512) {
        int hh = bid & 127, layer = bid >> 7;
        float2* data = (float2*)smem;
        float* ktmp = smem + 8192;
        const float2* src = at_roots + ((size_t)layer * Hdim + hh) * Lseq;
#pragma unroll
        for (int k = 0; k < 8; k++) {
            int l = t + 256 * k;
            data[sw(l)] = src[l];
        }
        __syncthreads();
        if (t < 128) {
            float2 v[16];
#pragma unroll
            for (int k = 0; k < 16; k++) v[k] = data[sw(t + 128 * k)];
            fft16_dif<true>(v);
#pragma unroll
            for (int i = 1; i < 16; i++) v[i] = cmulc(v[i], twget(tw, 2 * t * BR4[i]));
#pragma unroll
            for (int i = 0; i < 16; i++) data[sw(i * 128 + t)] = v[i];
        }
        __syncthreads();
        if (t < 128) {
            int i2 = t >> 3, j0 = t & 7;
            int base2 = i2 * 128 + j0;
            float2 v[16];
#pragma unroll
            for (int k = 0; k < 16; k++) v[k] = data[sw(base2 + 8 * k)];
            fft16_dif<true>(v);
#pragma unroll
            for (int i = 1; i < 16; i++) v[i] = cmulc(v[i], twget(tw, 32 * j0 * BR4[i]));
#pragma unroll
            for (int i = 0; i < 16; i++) data[sw(base2 + 8 * i)] = v[i];
        }
        __syncthreads();
        {
            float2 v8[8];
#pragma unroll
            for (int k = 0; k < 8; k++) v8[k] = data[sw(t * 8 + k)];
            fft8_dif<true>(v8);
            int r = BR4[t >> 4], s = BR4[t & 15];
#pragma unroll
            for (int i = 0; i < 8; i++) {
                int l = r + 16 * s + 256 * BR3[i];
                ktmp[l] = v8[i].x * (1.0f / 2048.0f);
            }
        }
        __syncthreads();
        {
            float2 vin[8];
#pragma unroll
            for (int k = 0; k < 8; k++) vin[k] = make_float2(ktmp[t + 256 * k], 0.f);
            fft4096_passA_hz(data, tw, t, vin);
        }
        fft4096_fwd_BC(data, tw, t);
        float2* dst = Kd1 + ((size_t)layer * Hdim + hh) * 4096;
#pragma unroll
        for (int k = 0; k < 16; k++) {
            int p = t + 256 * k;
            dst[p] = data[sw(p)];  // plain slot-order store, coalesced
        }
    } else {
        // ---- encoder + fused LN ----
        int r0 = (bid - 512) * 16;
        float* ws = smem;
        float* xst = smem + 8320;
        float* dots = smem + 9600;
        float2* mv = (float2*)(smem + 11648);
        for (int i = t; i < 128 * 64; i += 256) ws[(i >> 6) * 65 + (i & 63)] = enc_w[i];
        for (int i = t; i < 16 * 64; i += 256) {
            int r = i >> 6, k = i & 63;
            xst[k * 20 + r] = x[(size_t)(r0 + r) * 64 + k];
        }
        __syncthreads();
        int o = t & 127, half = t >> 7;
        float acc[8];
        float bo = enc_b[o];
#pragma unroll
        for (int j = 0; j < 8; j++) acc[j] = bo;
        for (int k = 0; k < 64; k++) {
            float wv = ws[o * 65 + k];
            float4 xa = *(const float4*)&xst[k * 20 + half * 8];
            float4 xb = *(const float4*)&xst[k * 20 + half * 8 + 4];
            acc[0] += wv * xa.x; acc[1] += wv * xa.y; acc[2] += wv * xa.z; acc[3] += wv * xa.w;
            acc[4] += wv * xb.x; acc[5] += wv * xb.y; acc[6] += wv * xb.z; acc[7] += wv * xb.w;
        }
#pragma unroll
        for (int j = 0; j < 8; j++) dots[(half * 8 + j) * 128 + o] = acc[j];
        __syncthreads();
        {
            int row = t >> 4, lane = t & 15;
            float s1 = 0.f, s2 = 0.f;
#pragma unroll
            for (int i = 0; i < 8; i++) {
                float v = dots[row * 128 + lane * 8 + i];
                s1 += v; s2 += v * v;
            }
#pragma unroll
            for (int m = 1; m < 16; m <<= 1) { s1 += __shfl_xor(s1, m); s2 += __shfl_xor(s2, m); }
            if (lane == 0) {
                float mu = s1 * (1.0f / 128.0f);
                float var = s2 * (1.0f / 128.0f) - mu * mu;
                mv[row] = make_float2(mu, fast_rsq(var + 1e-5f));
            }
        }
        __syncthreads();
        int c = t & 127;
        int bb = r0 >> 11, l0 = r0 & 2047;
        float nwc = nw[c], nbc = nb[c];
        float hnv[8];
#pragma unroll
        for (int j = 0; j < 8; j++) {
            int r = half * 8 + j;
            float v = dots[r * 128 + c];
            h[(size_t)(r0 + r) * Hdim + c] = v;
            float2 m = mv[r];
            hnv[j] = (v - m.x) * m.y * nwc + nbc;
        }
        float* dst = hnT + ((size_t)bb * Hdim + c) * Lseq + l0 + half * 8;
        *(float4*)dst = make_float4(hnv[0], hnv[1], hnv[2], hnv[3]);
        *(float4*)(dst + 4) = make_float4(hnv[4], hnv[5], hnv[6], hnv[7]);
    }
}

// ---------------- FFT convolution: batch-pair packing, radix-16^3, pruned A/A' ----------
// z = u[b0][h] + i*u[b1][h] (same channel, same K): by linearity y_b0=Re, y_b1=Im.
// Pointwise = Z[p]*Kd[h][p]/4096 in slot order (coalesced Kd, no untangle).
__global__ __launch_bounds__(256) void conv_kernel(float* __restrict__ hnT,
                                                   const float2* __restrict__ Kd1,
                                                   const float* __restrict__ dvec,
                                                   const float2* __restrict__ tw) {
    int h = blockIdx.x, bp = blockIdx.y, t = threadIdx.x;
    __shared__ float2 data[4096];
    float* u0 = hnT + ((size_t)(2 * bp) * Hdim + h) * Lseq;
    float* u1 = hnT + ((size_t)(2 * bp + 1) * Hdim + h) * Lseq;
    float2 ureg[8];
    {   // pruned pass A: input upper half zero, from registers
        float2 vin[8];
#pragma unroll
        for (int k = 0; k < 8; k++) {
            int l = t + 256 * k;
            float2 u2 = make_float2(u0[l], u1[l]);
            ureg[k] = u2;
            vin[k] = u2;
        }
        fft4096_passA_hz(data, tw, t, vin);
    }
    fft4096_fwd_BC(data, tw, t);
    // pointwise: slot order, coalesced Kd reads
    const float2* Kp = Kd1 + (size_t)h * 4096;
    const float scale = 1.0f / 4096.0f;
#pragma unroll
    for (int k = 0; k < 16; k++) {
        int p = t + 256 * k;
        float2 Z = data[sw(p)];
        float2 Kv = Kp[p];
        float2 W = cmulf(Z, Kv);
        data[sw(p)] = make_float2(W.x * scale, W.y * scale);
    }
    __syncthreads();
    {   // inverse pass C'
        float2 v[16];
#pragma unroll
        for (int i = 0; i < 16; i++) v[i] = data[sw(t * 16 + i)];
        fft16_dit<true>(v);
#pragma unroll
        for (int i = 0; i < 16; i++) data[sw(t * 16 + i)] = v[i];
    }
    __syncthreads();
    {   // inverse pass B'
        int j0 = t & 15;
        int base2 = (t >> 4) * 256 + j0;
        float2 v[16];
        v[0] = data[sw(base2)];
#pragma unroll
        for (int i = 1; i < 16; i++)
            v[i] = cmulc(data[sw(base2 + 16 * i)], twget(tw, 16 * j0 * BR4[i]));
        fft16_dit<true>(v);
#pragma unroll
        for (int i = 0; i < 16; i++) data[sw(base2 + 16 * i)] = v[i];
    }
    __syncthreads();
    {   // inverse pass A': final stage pruned to the needed output half (l < 2048)
        float2 v[16];
        v[0] = data[sw(t)];
#pragma unroll
        for (int i = 1; i < 16; i++)
            v[i] = cmulc(data[sw(i * 256 + t)], twget(tw, t * BR4[i]));
#pragma unroll
        for (int mi = 3; mi >= 1; mi--) {
            const int m = 8 >> mi;
#pragma unroll
            for (int g = 0; g < 16; g += 2 * m) {
#pragma unroll
                for (int j = 0; j < m; j++) {
                    float wr = W16R[j << mi], wi = -W16I[j << mi];
                    float2 a = v[g + j], bb2 = v[g + j + m];
                    float bx = bb2.x * wr - bb2.y * wi, by = bb2.x * wi + bb2.y * wr;
                    v[g + j] = make_float2(a.x + bx, a.y + by);
                    v[g + j + m] = make_float2(a.x - bx, a.y - by);
                }
            }
        }
#pragma unroll
        for (int j = 0; j < 8; j++) {  // only sums: outputs l = t+256j < 2048
            float wr = W16R[j], wi = -W16I[j];
            float2 bb2 = v[j + 8];
            float bx = bb2.x * wr - bb2.y * wi, by = bb2.x * wi + bb2.y * wr;
            v[j] = make_float2(v[j].x + bx, v[j].y + by);
        }
        float dcoef = dvec[h];
#pragma unroll
        for (int k = 0; k < 8; k++) {
            int l = t + 256 * k;
            u0[l] = gelu_f(v[k].x + ureg[k].x * dcoef);
            u1[l] = gelu_f(v[k].y + ureg[k].y * dcoef);
        }
    }
}

// ---------------- gated MLP via bf16 MFMA + residual + fused LN: 32 rows/block ----------------
__global__ __launch_bounds__(256) void mlp_kernel(const float* __restrict__ yT,
                                                  float* __restrict__ h,
                                                  float* __restrict__ hnT,
                                                  const __bf16* __restrict__ w1b,
                                                  const __bf16* __restrict__ w2b,
                                                  const float* __restrict__ b1,
                                                  const float* __restrict__ b2,
                                                  const float* __restrict__ nw,
                                                  const float* __restrict__ nb,
                                                  int do_ln) {
    int r0 = blockIdx.x * 32;
    int t = threadIdx.x;
    int wave = t >> 6, lane = t & 63;
    __shared__ __align__(16) __bf16 ybf[32 * 136];
    __shared__ float dots[32 * 132];
    __shared__ float2 mv[32];
    int bb = r0 >> 11, l0 = r0 & 2047;
    for (int i = t; i < 32 * 128; i += 256) {
        int r = i & 31, k = i >> 5;
        ybf[r * 136 + k] = (__bf16)yT[((size_t)bb * Hdim + k) * Lseq + l0 + r];
    }
    __syncthreads();
    int m = lane & 31, half = lane >> 5;
    bf16x8 a[8];
#pragma unroll
    for (int kk = 0; kk < 8; kk++)
        a[kk] = *(const bf16x8*)&ybf[m * 136 + kk * 16 + half * 8];
    int out = 32 * wave + m;
    const __bf16* w1r = w1b + (size_t)out * 128 + half * 8;
    const __bf16* w2r = w2b + (size_t)out * 128 + half * 8;
    f32x16 acc1, acc2;
#pragma unroll
    for (int i = 0; i < 16; i++) { acc1[i] = 0.f; acc2[i] = 0.f; }
#pragma unroll
    for (int kk = 0; kk < 8; kk++) {
        bf16x8 bw1 = *(const bf16x8*)(w1r + kk * 16);
        bf16x8 bw2 = *(const bf16x8*)(w2r + kk * 16);
        acc1 = __builtin_amdgcn_mfma_f32_32x32x16_bf16(a[kk], bw1, acc1, 0, 0, 0);
        acc2 = __builtin_amdgcn_mfma_f32_32x32x16_bf16(a[kk], bw2, acc2, 0, 0, 0);
    }
    float bias1 = b1[out], bias2 = b2[out];
#pragma unroll
    for (int reg = 0; reg < 16; reg++) {
        int row = (reg & 3) + 8 * (reg >> 2) + 4 * half;
        float v1 = acc1[reg] + bias1;
        float v2 = acc2[reg] + bias2;
        float g = fast_rcp(1.0f + __expf(-v2));
        float hv = h[(size_t)(r0 + row) * Hdim + out] + v1 * g;
        dots[row * 132 + out] = hv;
    }
    __syncthreads();
    if (do_ln) {
        int row = t >> 3, lane8 = t & 7;
        float s1 = 0.f, s2 = 0.f;
        int base = row * 132 + lane8 * 16;
#pragma unroll
        for (int q = 0; q < 4; q++) {
            float4 v4 = *(const float4*)&dots[base + 4 * q];
            s1 += v4.x + v4.y + v4.z + v4.w;
            s2 += v4.x * v4.x + v4.y * v4.y + v4.z * v4.z + v4.w * v4.w;
        }
#pragma unroll
        for (int mm = 1; mm < 8; mm <<= 1) { s1 += __shfl_xor(s1, mm); s2 += __shfl_xor(s2, mm); }
        if (lane8 == 0) {
            float mu = s1 * (1.0f / 128.0f);
            float var = s2 * (1.0f / 128.0f) - mu * mu;
            mv[row] = make_float2(mu, fast_rsq(var + 1e-5f));
        }
        __syncthreads();
        int o = t & 127, rh = t >> 7;
        float nwc = nw[o], nbc = nb[o];
        float hnv[16];
#pragma unroll
        for (int j = 0; j < 16; j++) {
            int r = rh * 16 + j;
            float hvv = dots[r * 132 + o];
            h[(size_t)(r0 + r) * Hdim + o] = hvv;
            float2 mvv = mv[r];
            hnv[j] = (hvv - mvv.x) * mvv.y * nwc + nbc;
        }
        float* dst = hnT + ((size_t)bb * Hdim + o) * Lseq + l0 + rh * 16;
        *(float4*)(dst)      = make_float4(hnv[0],  hnv[1],  hnv[2],  hnv[3]);
        *(float4*)(dst + 4)  = make_float4(hnv[4],  hnv[5],  hnv[6],  hnv[7]);
        *(float4*)(dst + 8)  = make_float4(hnv[8],  hnv[9],  hnv[10], hnv[11]);
        *(float4*)(dst + 12) = make_float4(hnv[12], hnv[13], hnv[14], hnv[15]);
    } else {
        int o = t & 127, rh = t >> 7;
#pragma unroll
        for (int j = 0; j < 16; j++) {
            int r = rh * 16 + j;
            h[(size_t)(r0 + r) * Hdim + o] = dots[r * 132 + o];
        }
    }
}

// ---------------- decoder: 32 rows/block ----------------
__global__ __launch_bounds__(256) void decoder_kernel(const float* __restrict__ h,
                                                      const float* __restrict__ w,
                                                      const float* __restrict__ b,
                                                      float* __restrict__ out) {
    int r0 = blockIdx.x * 32;
    int t = threadIdx.x;
    __shared__ float ws[64 * 129];
    __shared__ __align__(16) float hst[128 * 36];
    for (int i = t; i < 64 * 128; i += 256) ws[(i >> 7) * 129 + (i & 127)] = w[i];
    for (int i = t; i < 32 * 128; i += 256) {
        int r = i >> 7, k = i & 127;
        hst[k * 36 + r] = h[(size_t)(r0 + r) * Hdim + k];
    }
    __syncthreads();
    int o = t & 63, q = t >> 6;
    float acc[8];
    float bo = b[o];
#pragma unroll
    for (int j = 0; j < 8; j++) acc[j] = bo;
    for (int k = 0; k < 128; k++) {
        float wv = ws[o * 129 + k];
        float4 ha = *(const float4*)&hst[k * 36 + q * 8];
        float4 hb = *(const float4*)&hst[k * 36 + q * 8 + 4];
        acc[0] += wv * ha.x; acc[1] += wv * ha.y; acc[2] += wv * ha.z; acc[3] += wv * ha.w;
        acc[4] += wv * hb.x; acc[5] += wv * hb.y; acc[6] += wv * hb.z; acc[7] += wv * hb.w;
    }
#pragma unroll
    for (int j = 0; j < 8; j++) out[(size_t)(r0 + q * 8 + j) * 64 + o] = acc[j];
}

extern "C" void kernel_launch(void* const* d_in, const int* in_sizes, int n_in,
                              void* d_out, int out_size, void* d_ws, size_t ws_size,
                              hipStream_t stream) {
    const float* x      = (const float*)d_in[0];
    const float* enc_w  = (const float*)d_in[2];
    const float* enc_b  = (const float*)d_in[3];
    const float* dec_w  = (const float*)d_in[4];
    const float* dec_b  = (const float*)d_in[5];
    const float* lam_re = (const float*)d_in[6];
    const float* lam_im = (const float*)d_in[7];
    const float* p_re   = (const float*)d_in[8];
    const float* p_im   = (const float*)d_in[9];
    const float* b_re   = (const float*)d_in[10];
    const float* b_im   = (const float*)d_in[11];
    const float* c_re   = (const float*)d_in[12];
    const float* c_im   = (const float*)d_in[13];
    const float* dvec   = (const float*)d_in[14];
    const float* lstep  = (const float*)d_in[15];
    const float* norm_w = (const float*)d_in[16];
    const float* norm_b = (const float*)d_in[17];
    const float* w1     = (const float*)d_in[18];
    const float* b1     = (const float*)d_in[19];
    const float* w2     = (const float*)d_in[20];
    const float* b2     = (const float*)d_in[21];
    float* out = (float*)d_out;

    char* ws = (char*)d_ws;
    float2* tw  = (float2*)ws;  ws += 2048 * sizeof(float2);
    float*  h   = (float*)ws;   ws += (size_t)Bsz * Lseq * Hdim * sizeof(float);
    float*  hnT = (float*)ws;   ws += (size_t)Bsz * Lseq * Hdim * sizeof(float);
    float2* atr = (float2*)ws;  ws += (size_t)NLAYERS * Hdim * Lseq * sizeof(float2);
    float2* Kd1 = (float2*)ws;  ws += (size_t)NLAYERS * Hdim * 4096 * sizeof(float2);
    __bf16* wbf = (__bf16*)ws;  ws += (size_t)NLAYERS * 2 * Hdim * Hdim * sizeof(__bf16);

    const int nrows = Bsz * Lseq;  // 16384

    prep_kernel<<<8 + 256 + 2048, 256, 0, stream>>>(
        lam_re, lam_im, p_re, p_im, b_re, b_im, c_re, c_im, lstep, w1, w2, tw, wbf, atr);
    kfft_enc_kernel<<<512 + nrows / 16, 256, 0, stream>>>(
        atr, Kd1, tw, x, enc_w, enc_b, norm_w, norm_b, h, hnT);
    for (int L = 0; L < NLAYERS; L++) {
        conv_kernel<<<dim3(Hdim, Bsz / 2), 256, 0, stream>>>(
            hnT, Kd1 + (size_t)L * Hdim * 4096, dvec + L * Hdim, tw);
        int do_ln = (L < NLAYERS - 1) ? 1 : 0;
        const float* nwn = norm_w + ((L + 1) % NLAYERS) * Hdim;
        const float* nbn = norm_b + ((L + 1) % NLAYERS) * Hdim;
        const __bf16* w1bL = wbf + (size_t)L * 2 * Hdim * Hdim;
        const __bf16* w2bL = w1bL + Hdim * Hdim;
        mlp_kernel<<<nrows / 32, 256, 0, stream>>>(hnT, h, hnT, w1bL, w2bL,
                                                   b1 + L * Hdim, b2 + L * Hdim,
                                                   nwn, nbn, do_ln);
    }
    decoder_kernel<<<nrows / 32, 256, 0, stream>>>(h, dec_w, dec_b, out);
}

// Round 16
// 292.851 us; speedup vs baseline: 1.0929x; 1.0596x over previous
//
#include <hip/hip_runtime.h>
#include <hip/hip_bf16.h>

// S4 (DPLR) forward, B=8 L=2048 IN=OUT=64 H=128 N=64, 4 layers.
// R16: (1) decoder fused into last mlp launch via bf16 MFMA on the LDS-resident
// h tile (rows match exactly; last-layer h global write eliminated);
// (2) conv prefetches its 16 Kd float2 loads into registers before the forward
// FFT so the fetch latency hides under compute. Rest = R15 (batch-pair conv).

#define Bsz 8
#define Lseq 2048
#define Hdim 128
#define Npol 64
#define NLAYERS 4

typedef __bf16 bf16x8 __attribute__((ext_vector_type(8)));
typedef float f32x16 __attribute__((ext_vector_type(16)));

__device__ __forceinline__ float fast_rcp(float x) { return __builtin_amdgcn_rcpf(x); }
__device__ __forceinline__ float fast_rsq(float x) { return __builtin_amdgcn_rsqf(x); }

__device__ __forceinline__ float2 cmulf(float2 a, float2 b) {
    return make_float2(a.x * b.x - a.y * b.y, a.x * b.y + a.y * b.x);
}
__device__ __forceinline__ float2 cmulc(float2 a, float2 b) {  // a * conj(b)
    return make_float2(a.x * b.x + a.y * b.y, a.y * b.x - a.x * b.y);
}

__device__ __forceinline__ float gelu_f(float v) {
    float z = 0.7978845608028654f * (v + 0.044715f * v * v * v);
    float e = __expf(2.0f * z);
    return v - v * fast_rcp(e + 1.0f);
}

// XOR swizzle: strides 1/16/256 all conflict-uniform for the 4096 arrays.
__device__ __forceinline__ int sw(int i) { return (i & ~15) | ((i ^ (i >> 4)) & 15); }

static __device__ const float W16R[8] = {1.f, 0.9238795325f, 0.7071067812f, 0.3826834324f,
                                         0.f, -0.3826834324f, -0.7071067812f, -0.9238795325f};
static __device__ const float W16I[8] = {0.f, -0.3826834324f, -0.7071067812f, -0.9238795325f,
                                         -1.f, -0.9238795325f, -0.7071067812f, -0.3826834324f};
static __device__ const int BR4[16] = {0, 8, 4, 12, 2, 10, 6, 14, 1, 9, 5, 13, 3, 11, 7, 15};
static __device__ const int BR3[8] = {0, 4, 2, 6, 1, 5, 3, 7};

__device__ __forceinline__ float2 twget(const float2* __restrict__ tw, int e) {
    float2 w = tw[e & 2047];
    if (e & 2048) { w.x = -w.x; w.y = -w.y; }
    return w;
}

template <bool INV>
__device__ __forceinline__ void fft16_dif(float2 v[16]) {
#pragma unroll
    for (int mi = 0; mi < 4; mi++) {
        const int m = 8 >> mi;
#pragma unroll
        for (int g = 0; g < 16; g += 2 * m) {
#pragma unroll
            for (int j = 0; j < m; j++) {
                float wr = W16R[j << mi];
                float wi = INV ? -W16I[j << mi] : W16I[j << mi];
                float2 a = v[g + j], b = v[g + j + m];
                float dx = a.x - b.x, dy = a.y - b.y;
                v[g + j] = make_float2(a.x + b.x, a.y + b.y);
                v[g + j + m] = make_float2(dx * wr - dy * wi, dx * wi + dy * wr);
            }
        }
    }
}

template <bool INV>
__device__ __forceinline__ void fft16_dit(float2 v[16]) {
#pragma unroll
    for (int mi = 3; mi >= 0; mi--) {
        const int m = 8 >> mi;
#pragma unroll
        for (int g = 0; g < 16; g += 2 * m) {
#pragma unroll
            for (int j = 0; j < m; j++) {
                float wr = W16R[j << mi];
                float wi = INV ? -W16I[j << mi] : W16I[j << mi];
                float2 a = v[g + j], b = v[g + j + m];
                float bx = b.x * wr - b.y * wi, by = b.x * wi + b.y * wr;
                v[g + j] = make_float2(a.x + bx, a.y + by);
                v[g + j + m] = make_float2(a.x - bx, a.y - by);
            }
        }
    }
}

template <bool INV>
__device__ __forceinline__ void fft8_dif(float2 v[8]) {
#pragma unroll
    for (int mi = 0; mi < 3; mi++) {
        const int m = 4 >> mi;
#pragma unroll
        for (int g = 0; g < 8; g += 2 * m) {
#pragma unroll
            for (int j = 0; j < m; j++) {
                float wr = W16R[j << (mi + 1)];
                float wi = INV ? -W16I[j << (mi + 1)] : W16I[j << (mi + 1)];
                float2 a = v[g + j], b = v[g + j + m];
                float dx = a.x - b.x, dy = a.y - b.y;
                v[g + j] = make_float2(a.x + b.x, a.y + b.y);
                v[g + j + m] = make_float2(dx * wr - dy * wi, dx * wi + dy * wr);
            }
        }
    }
}

// Pass A of the zero-padded (upper half) forward 4096 FFT, input in registers.
__device__ __forceinline__ void fft4096_passA_hz(float2* data, const float2* __restrict__ tw,
                                                 int t, const float2 vin[8]) {
    float2 v[16];
#pragma unroll
    for (int j = 0; j < 8; j++) v[j] = vin[j];
#pragma unroll
    for (int j = 0; j < 8; j++)
        v[j + 8] = cmulf(v[j], make_float2(W16R[j], W16I[j]));
#pragma unroll
    for (int mi = 1; mi < 4; mi++) {
        const int m = 8 >> mi;
#pragma unroll
        for (int g = 0; g < 16; g += 2 * m) {
#pragma unroll
            for (int j = 0; j < m; j++) {
                float wr = W16R[j << mi], wi = W16I[j << mi];
                float2 a = v[g + j], b = v[g + j + m];
                float dx = a.x - b.x, dy = a.y - b.y;
                v[g + j] = make_float2(a.x + b.x, a.y + b.y);
                v[g + j + m] = make_float2(dx * wr - dy * wi, dx * wi + dy * wr);
            }
        }
    }
#pragma unroll
    for (int i = 1; i < 16; i++) v[i] = cmulf(v[i], twget(tw, t * BR4[i]));
#pragma unroll
    for (int i = 0; i < 16; i++) data[sw(i * 256 + t)] = v[i];
}

// Passes B and C of the forward 4096 FFT (leading barrier included).
__device__ __forceinline__ void fft4096_fwd_BC(float2* data, const float2* __restrict__ tw, int t) {
    __syncthreads();
    {
        int j0 = t & 15;
        int base = (t >> 4) * 256 + j0;
        float2 v[16];
#pragma unroll
        for (int k = 0; k < 16; k++) v[k] = data[sw(base + 16 * k)];
        fft16_dif<false>(v);
#pragma unroll
        for (int i = 1; i < 16; i++) v[i] = cmulf(v[i], twget(tw, 16 * j0 * BR4[i]));
#pragma unroll
        for (int i = 0; i < 16; i++) data[sw(base + 16 * i)] = v[i];
    }
    __syncthreads();
    {
        float2 v[16];
#pragma unroll
        for (int k = 0; k < 16; k++) v[k] = data[sw(t * 16 + k)];
        fft16_dif<false>(v);
#pragma unroll
        for (int i = 0; i < 16; i++) data[sw(t * 16 + i)] = v[i];
    }
    __syncthreads();
}

// ---------------- prep: twiddle + weight-bf16 (w1,w2,dec_w) + spectrum ----------------
__global__ __launch_bounds__(256, 4) void prep_kernel(const float* __restrict__ lam_re,
                                                      const float* __restrict__ lam_im,
                                                      const float* __restrict__ p_re,
                                                      const float* __restrict__ p_im,
                                                      const float* __restrict__ b_re,
                                                      const float* __restrict__ b_im,
                                                      const float* __restrict__ c_re,
                                                      const float* __restrict__ c_im,
                                                      const float* __restrict__ log_step,
                                                      const float* __restrict__ w1,
                                                      const float* __restrict__ w2,
                                                      const float* __restrict__ dec_w,
                                                      float2* __restrict__ tw,
                                                      __bf16* __restrict__ wbf,
                                                      __bf16* __restrict__ decbf,
                                                      float2* __restrict__ at_roots) {
    int bid = blockIdx.x, t = threadIdx.x;
    if (bid < 8) {
        int k = bid * 256 + t;
        if (k < 2048) {
            double a = -6.283185307179586476925286766559 * (double)k / 4096.0;
            tw[k] = make_float2((float)cos(a), (float)sin(a));
        }
        return;
    }
    if (bid < 264) {
        int i = (bid - 8) * 256 + t;
        int layer = i >> 14, rem = i & 16383;
        wbf[((size_t)layer * 2) * 16384 + rem] = (__bf16)w1[i];
        wbf[((size_t)layer * 2 + 1) * 16384 + rem] = (__bf16)w2[i];
        return;
    }
    if (bid < 296) {  // dec_w (64x128) -> bf16
        int i = (bid - 264) * 256 + t;
        decbf[i] = (__bf16)dec_w[i];
        return;
    }
    int s = bid - 296;
    int h = s & 127, layer = (s >> 7) & 3;
    int l0 = 512 * (s >> 9);
    __shared__ __align__(16) float4 polA[Npol];
    __shared__ __align__(16) float4 polB[Npol];
    __shared__ float n11S[Npol];
    int baseP = (layer * Hdim + h) * Npol;
    if (t < Npol) {
        int n = t;
        float lr = lam_re[baseP + n], li = lam_im[baseP + n];
        float pr = p_re[baseP + n], pi = p_im[baseP + n];
        float br = b_re[baseP + n], bi = b_im[baseP + n];
        float cr = c_re[baseP + n], ci = c_im[baseP + n];
        polA[n] = make_float4(lr, li, cr * br + ci * bi, cr * bi - ci * br);
        polB[n] = make_float4(cr * pr + ci * pi, cr * pi - ci * pr,
                              pr * br + pi * bi, pr * bi - pi * br);
        n11S[n] = pr * pr + pi * pi;
    }
    __syncthreads();
    float step = expf(log_step[layer * Hdim + h]);
    float gs = 2.0f / step;

    float gr[2], gi[2];
#pragma unroll
    for (int j = 0; j < 2; j++) {
        int l = l0 + t + 256 * j;
        float ang = -6.283185307179586f * (float)l / (float)Lseq;
        float wr = cosf(ang), wi = sinf(ang);  // fp32 omega on purpose (range)
        float dr = 1.0f + wr, di = wi;
        float invd2 = fast_rcp(dr * dr + di * di);
        float nr = 1.0f - wr, ni = -wi;
        gr[j] = gs * (nr * dr + ni * di) * invd2;
        gi[j] = gs * (ni * dr - nr * di) * invd2;
    }
    float k00x[2] = {0, 0}, k00y[2] = {0, 0};
    float k01x[2] = {0, 0}, k01y[2] = {0, 0};
    float k10x[2] = {0, 0}, k10y[2] = {0, 0};
    float k11x[2] = {0, 0}, k11y[2] = {0, 0};
#pragma unroll 4
    for (int n = 0; n < Npol; n++) {
        float4 A = polA[n];
        float4 B = polB[n];
        float n11 = n11S[n];
#pragma unroll
        for (int j = 0; j < 2; j++) {
            float er = gr[j] - A.x, ei = gi[j] - A.y;
            float inv2 = fast_rcp(fmaf(er, er, ei * ei));
            float ir = er * inv2;
            float mi = ei * inv2;
            k00x[j] = fmaf(A.z, ir, fmaf(A.w, mi, k00x[j]));
            k00y[j] = fmaf(A.w, ir, fmaf(-A.z, mi, k00y[j]));
            k01x[j] = fmaf(B.x, ir, fmaf(B.y, mi, k01x[j]));
            k01y[j] = fmaf(B.y, ir, fmaf(-B.x, mi, k01y[j]));
            k10x[j] = fmaf(B.z, ir, fmaf(B.w, mi, k10x[j]));
            k10y[j] = fmaf(B.w, ir, fmaf(-B.z, mi, k10y[j]));
            k11x[j] = fmaf(n11, ir, k11x[j]);
            k11y[j] = fmaf(-n11, mi, k11y[j]);
        }
    }
#pragma unroll
    for (int j = 0; j < 2; j++) {
        int l = l0 + t + 256 * j;
        float ang = -6.283185307179586f * (float)l / (float)Lseq;
        float wr = cosf(ang), wi = sinf(ang);
        float dr = 1.0f + wr, di = wi;
        float invd2 = fast_rcp(dr * dr + di * di);
        float cr2 = 2.0f * dr * invd2, ci2 = -2.0f * di * invd2;
        float wr2 = 1.0f + k11x[j], wi2 = k11y[j];
        float w2inv = fast_rcp(fmaf(wr2, wr2, wi2 * wi2));
        float vr = wr2 * w2inv, vi = -wi2 * w2inv;
        float t1x = k01x[j] * k10x[j] - k01y[j] * k10y[j];
        float t1y = k01x[j] * k10y[j] + k01y[j] * k10x[j];
        float t2x = t1x * vr - t1y * vi, t2y = t1x * vi + t1y * vr;
        float ex = k00x[j] - t2x, ey = k00y[j] - t2y;
        at_roots[((size_t)layer * Hdim + h) * Lseq + l] =
            make_float2(cr2 * ex - ci2 * ey, cr2 * ey + ci2 * ex);
    }
}

// ---------------- kfft + encoder merged ----------------
// kfft: blocks [0,512); encoder: blocks [512,1536).
__global__ __launch_bounds__(256) void kfft_enc_kernel(const float2* __restrict__ at_roots,
                                                       float2* __restrict__ Kd1,
                                                       const float2* __restrict__ tw,
                                                       const float* __restrict__ x,
                                                       const float* __restrict__ enc_w,
                                                       const float* __restrict__ enc_b,
                                                       const float* __restrict__ nw,
                                                       const float* __restrict__ nb,
                                                       float* __restrict__ h,
                                                       float* __restrict__ hnT) {
    __shared__ __align__(16) float smem[11712];
    int bid = blockIdx.x, t = threadIdx.x;
    if (bid < 512) {
        int hh = bid & 127, layer = bid >> 7;
        float2* data = (float2*)smem;
        float* ktmp = smem + 8192;
        const float2* src = at_roots + ((size_t)layer * Hdim + hh) * Lseq;
#pragma unroll
        for (int k = 0; k < 8; k++) {
            int l = t + 256 * k;
            data[sw(l)] = src[l];
        }
        __syncthreads();
        if (t < 128) {
            float2 v[16];
#pragma unroll
            for (int k = 0; k < 16; k++) v[k] = data[sw(t + 128 * k)];
            fft16_dif<true>(v);
#pragma unroll
            for (int i = 1; i < 16; i++) v[i] = cmulc(v[i], twget(tw, 2 * t * BR4[i]));
#pragma unroll
            for (int i = 0; i < 16; i++) data[sw(i * 128 + t)] = v[i];
        }
        __syncthreads();
        if (t < 128) {
            int i2 = t >> 3, j0 = t & 7;
            int base2 = i2 * 128 + j0;
            float2 v[16];
#pragma unroll
            for (int k = 0; k < 16; k++) v[k] = data[sw(base2 + 8 * k)];
            fft16_dif<true>(v);
#pragma unroll
            for (int i = 1; i < 16; i++) v[i] = cmulc(v[i], twget(tw, 32 * j0 * BR4[i]));
#pragma unroll
            for (int i = 0; i < 16; i++) data[sw(base2 + 8 * i)] = v[i];
        }
        __syncthreads();
        {
            float2 v8[8];
#pragma unroll
            for (int k = 0; k < 8; k++) v8[k] = data[sw(t * 8 + k)];
            fft8_dif<true>(v8);
            int r = BR4[t >> 4], s = BR4[t & 15];
#pragma unroll
            for (int i = 0; i < 8; i++) {
                int l = r + 16 * s + 256 * BR3[i];
                ktmp[l] = v8[i].x * (1.0f / 2048.0f);
            }
        }
        __syncthreads();
        {
            float2 vin[8];
#pragma unroll
            for (int k = 0; k < 8; k++) vin[k] = make_float2(ktmp[t + 256 * k], 0.f);
            fft4096_passA_hz(data, tw, t, vin);
        }
        fft4096_fwd_BC(data, tw, t);
        float2* dst = Kd1 + ((size_t)layer * Hdim + hh) * 4096;
#pragma unroll
        for (int k = 0; k < 16; k++) {
            int p = t + 256 * k;
            dst[p] = data[sw(p)];
        }
    } else {
        // ---- encoder + fused LN ----
        int r0 = (bid - 512) * 16;
        float* ws = smem;
        float* xst = smem + 8320;
        float* dots = smem + 9600;
        float2* mv = (float2*)(smem + 11648);
        for (int i = t; i < 128 * 64; i += 256) ws[(i >> 6) * 65 + (i & 63)] = enc_w[i];
        for (int i = t; i < 16 * 64; i += 256) {
            int r = i >> 6, k = i & 63;
            xst[k * 20 + r] = x[(size_t)(r0 + r) * 64 + k];
        }
        __syncthreads();
        int o = t & 127, half = t >> 7;
        float acc[8];
        float bo = enc_b[o];
#pragma unroll
        for (int j = 0; j < 8; j++) acc[j] = bo;
        for (int k = 0; k < 64; k++) {
            float wv = ws[o * 65 + k];
            float4 xa = *(const float4*)&xst[k * 20 + half * 8];
            float4 xb = *(const float4*)&xst[k * 20 + half * 8 + 4];
            acc[0] += wv * xa.x; acc[1] += wv * xa.y; acc[2] += wv * xa.z; acc[3] += wv * xa.w;
            acc[4] += wv * xb.x; acc[5] += wv * xb.y; acc[6] += wv * xb.z; acc[7] += wv * xb.w;
        }
#pragma unroll
        for (int j = 0; j < 8; j++) dots[(half * 8 + j) * 128 + o] = acc[j];
        __syncthreads();
        {
            int row = t >> 4, lane = t & 15;
            float s1 = 0.f, s2 = 0.f;
#pragma unroll
            for (int i = 0; i < 8; i++) {
                float v = dots[row * 128 + lane * 8 + i];
                s1 += v; s2 += v * v;
            }
#pragma unroll
            for (int m = 1; m < 16; m <<= 1) { s1 += __shfl_xor(s1, m); s2 += __shfl_xor(s2, m); }
            if (lane == 0) {
                float mu = s1 * (1.0f / 128.0f);
                float var = s2 * (1.0f / 128.0f) - mu * mu;
                mv[row] = make_float2(mu, fast_rsq(var + 1e-5f));
            }
        }
        __syncthreads();
        int c = t & 127;
        int bb = r0 >> 11, l0 = r0 & 2047;
        float nwc = nw[c], nbc = nb[c];
        float hnv[8];
#pragma unroll
        for (int j = 0; j < 8; j++) {
            int r = half * 8 + j;
            float v = dots[r * 128 + c];
            h[(size_t)(r0 + r) * Hdim + c] = v;
            float2 m = mv[r];
            hnv[j] = (v - m.x) * m.y * nwc + nbc;
        }
        float* dst = hnT + ((size_t)bb * Hdim + c) * Lseq + l0 + half * 8;
        *(float4*)dst = make_float4(hnv[0], hnv[1], hnv[2], hnv[3]);
        *(float4*)(dst + 4) = make_float4(hnv[4], hnv[5], hnv[6], hnv[7]);
    }
}

// ---------------- FFT convolution: batch-pair packing, radix-16^3, Kd prefetch ----------
__global__ __launch_bounds__(256) void conv_kernel(float* __restrict__ hnT,
                                                   const float2* __restrict__ Kd1,
                                                   const float* __restrict__ dvec,
                                                   const float2* __restrict__ tw) {
    int h = blockIdx.x, bp = blockIdx.y, t = threadIdx.x;
    __shared__ float2 data[4096];
    float* u0 = hnT + ((size_t)(2 * bp) * Hdim + h) * Lseq;
    float* u1 = hnT + ((size_t)(2 * bp + 1) * Hdim + h) * Lseq;
    float2 ureg[8];
    float2 Kreg[16];
    const float2* Kp = Kd1 + (size_t)h * 4096;
    {   // pruned pass A: input upper half zero, from registers. Kd prefetch issued
        // alongside the u loads so its latency hides under the whole forward FFT.
        float2 vin[8];
#pragma unroll
        for (int k = 0; k < 8; k++) {
            int l = t + 256 * k;
            float2 u2 = make_float2(u0[l], u1[l]);
            ureg[k] = u2;
            vin[k] = u2;
        }
#pragma unroll
        for (int k = 0; k < 16; k++) Kreg[k] = Kp[t + 256 * k];
        fft4096_passA_hz(data, tw, t, vin);
    }
    fft4096_fwd_BC(data, tw, t);
    // pointwise: slot order, Kd already in registers
    const float scale = 1.0f / 4096.0f;
#pragma unroll
    for (int k = 0; k < 16; k++) {
        int p = t + 256 * k;
        float2 Z = data[sw(p)];
        float2 W = cmulf(Z, Kreg[k]);
        data[sw(p)] = make_float2(W.x * scale, W.y * scale);
    }
    __syncthreads();
    {   // inverse pass C'
        float2 v[16];
#pragma unroll
        for (int i = 0; i < 16; i++) v[i] = data[sw(t * 16 + i)];
        fft16_dit<true>(v);
#pragma unroll
        for (int i = 0; i < 16; i++) data[sw(t * 16 + i)] = v[i];
    }
    __syncthreads();
    {   // inverse pass B'
        int j0 = t & 15;
        int base2 = (t >> 4) * 256 + j0;
        float2 v[16];
        v[0] = data[sw(base2)];
#pragma unroll
        for (int i = 1; i < 16; i++)
            v[i] = cmulc(data[sw(base2 + 16 * i)], twget(tw, 16 * j0 * BR4[i]));
        fft16_dit<true>(v);
#pragma unroll
        for (int i = 0; i < 16; i++) data[sw(base2 + 16 * i)] = v[i];
    }
    __syncthreads();
    {   // inverse pass A': final stage pruned to the needed output half (l < 2048)
        float2 v[16];
        v[0] = data[sw(t)];
#pragma unroll
        for (int i = 1; i < 16; i++)
            v[i] = cmulc(data[sw(i * 256 + t)], twget(tw, t * BR4[i]));
#pragma unroll
        for (int mi = 3; mi >= 1; mi--) {
            const int m = 8 >> mi;
#pragma unroll
            for (int g = 0; g < 16; g += 2 * m) {
#pragma unroll
                for (int j = 0; j < m; j++) {
                    float wr = W16R[j << mi], wi = -W16I[j << mi];
                    float2 a = v[g + j], bb2 = v[g + j + m];
                    float bx = bb2.x * wr - bb2.y * wi, by = bb2.x * wi + bb2.y * wr;
                    v[g + j] = make_float2(a.x + bx, a.y + by);
                    v[g + j + m] = make_float2(a.x - bx, a.y - by);
                }
            }
        }
#pragma unroll
        for (int j = 0; j < 8; j++) {
            float wr = W16R[j], wi = -W16I[j];
            float2 bb2 = v[j + 8];
            float bx = bb2.x * wr - bb2.y * wi, by = bb2.x * wi + bb2.y * wr;
            v[j] = make_float2(v[j].x + bx, v[j].y + by);
        }
        float dcoef = dvec[h];
#pragma unroll
        for (int k = 0; k < 8; k++) {
            int l = t + 256 * k;
            u0[l] = gelu_f(v[k].x + ureg[k].x * dcoef);
            u1[l] = gelu_f(v[k].y + ureg[k].y * dcoef);
        }
    }
}

// ---------------- gated MLP via bf16 MFMA + residual + fused LN: 32 rows/block ----------------
__global__ __launch_bounds__(256) void mlp_kernel(const float* __restrict__ yT,
                                                  float* __restrict__ h,
                                                  float* __restrict__ hnT,
                                                  const __bf16* __restrict__ w1b,
                                                  const __bf16* __restrict__ w2b,
                                                  const float* __restrict__ b1,
                                                  const float* __restrict__ b2,
                                                  const float* __restrict__ nw,
                                                  const float* __restrict__ nb) {
    int r0 = blockIdx.x * 32;
    int t = threadIdx.x;
    int wave = t >> 6, lane = t & 63;
    __shared__ __align__(16) __bf16 ybf[32 * 136];
    __shared__ float dots[32 * 132];
    __shared__ float2 mv[32];
    int bb = r0 >> 11, l0 = r0 & 2047;
    for (int i = t; i < 32 * 128; i += 256) {
        int r = i & 31, k = i >> 5;
        ybf[r * 136 + k] = (__bf16)yT[((size_t)bb * Hdim + k) * Lseq + l0 + r];
    }
    __syncthreads();
    int m = lane & 31, half = lane >> 5;
    bf16x8 a[8];
#pragma unroll
    for (int kk = 0; kk < 8; kk++)
        a[kk] = *(const bf16x8*)&ybf[m * 136 + kk * 16 + half * 8];
    int out = 32 * wave + m;
    const __bf16* w1r = w1b + (size_t)out * 128 + half * 8;
    const __bf16* w2r = w2b + (size_t)out * 128 + half * 8;
    f32x16 acc1, acc2;
#pragma unroll
    for (int i = 0; i < 16; i++) { acc1[i] = 0.f; acc2[i] = 0.f; }
#pragma unroll
    for (int kk = 0; kk < 8; kk++) {
        bf16x8 bw1 = *(const bf16x8*)(w1r + kk * 16);
        bf16x8 bw2 = *(const bf16x8*)(w2r + kk * 16);
        acc1 = __builtin_amdgcn_mfma_f32_32x32x16_bf16(a[kk], bw1, acc1, 0, 0, 0);
        acc2 = __builtin_amdgcn_mfma_f32_32x32x16_bf16(a[kk], bw2, acc2, 0, 0, 0);
    }
    float bias1 = b1[out], bias2 = b2[out];
#pragma unroll
    for (int reg = 0; reg < 16; reg++) {
        int row = (reg & 3) + 8 * (reg >> 2) + 4 * half;
        float v1 = acc1[reg] + bias1;
        float v2 = acc2[reg] + bias2;
        float g = fast_rcp(1.0f + __expf(-v2));
        float hv = h[(size_t)(r0 + row) * Hdim + out] + v1 * g;
        dots[row * 132 + out] = hv;
    }
    __syncthreads();
    {
        int row = t >> 3, lane8 = t & 7;
        float s1 = 0.f, s2 = 0.f;
        int base = row * 132 + lane8 * 16;
#pragma unroll
        for (int q = 0; q < 4; q++) {
            float4 v4 = *(const float4*)&dots[base + 4 * q];
            s1 += v4.x + v4.y + v4.z + v4.w;
            s2 += v4.x * v4.x + v4.y * v4.y + v4.z * v4.z + v4.w * v4.w;
        }
#pragma unroll
        for (int mm = 1; mm < 8; mm <<= 1) { s1 += __shfl_xor(s1, mm); s2 += __shfl_xor(s2, mm); }
        if (lane8 == 0) {
            float mu = s1 * (1.0f / 128.0f);
            float var = s2 * (1.0f / 128.0f) - mu * mu;
            mv[row] = make_float2(mu, fast_rsq(var + 1e-5f));
        }
    }
    __syncthreads();
    {
        int o = t & 127, rh = t >> 7;
        float nwc = nw[o], nbc = nb[o];
        float hnv[16];
#pragma unroll
        for (int j = 0; j < 16; j++) {
            int r = rh * 16 + j;
            float hvv = dots[r * 132 + o];
            h[(size_t)(r0 + r) * Hdim + o] = hvv;
            float2 mvv = mv[r];
            hnv[j] = (hvv - mvv.x) * mvv.y * nwc + nbc;
        }
        float* dst = hnT + ((size_t)bb * Hdim + o) * Lseq + l0 + rh * 16;
        *(float4*)(dst)      = make_float4(hnv[0],  hnv[1],  hnv[2],  hnv[3]);
        *(float4*)(dst + 4)  = make_float4(hnv[4],  hnv[5],  hnv[6],  hnv[7]);
        *(float4*)(dst + 8)  = make_float4(hnv[8],  hnv[9],  hnv[10], hnv[11]);
        *(float4*)(dst + 12) = make_float4(hnv[12], hnv[13], hnv[14], hnv[15]);
    }
}

// ---------------- last layer: gated MLP + residual + fused DECODER (bf16 MFMA) ----------
// Same 32-row block as mlp; after residual, h tile lives in dots LDS. Restage as
// bf16 into ybf and run the decoder GEMM on waves 0-1. No h global write (decoder
// is its only consumer).
__global__ __launch_bounds__(256) void mlpdec_kernel(const float* __restrict__ yT,
                                                     const float* __restrict__ h,
                                                     const __bf16* __restrict__ w1b,
                                                     const __bf16* __restrict__ w2b,
                                                     const float* __restrict__ b1,
                                                     const float* __restrict__ b2,
                                                     const __bf16* __restrict__ decb,
                                                     const float* __restrict__ dec_bias,
                                                     float* __restrict__ out) {
    int r0 = blockIdx.x * 32;
    int t = threadIdx.x;
    int wave = t >> 6, lane = t & 63;
    __shared__ __align__(16) __bf16 ybf[32 * 136];
    __shared__ float dots[32 * 132];
    int bb = r0 >> 11, l0 = r0 & 2047;
    for (int i = t; i < 32 * 128; i += 256) {
        int r = i & 31, k = i >> 5;
        ybf[r * 136 + k] = (__bf16)yT[((size_t)bb * Hdim + k) * Lseq + l0 + r];
    }
    __syncthreads();
    int m = lane & 31, half = lane >> 5;
    bf16x8 a[8];
#pragma unroll
    for (int kk = 0; kk < 8; kk++)
        a[kk] = *(const bf16x8*)&ybf[m * 136 + kk * 16 + half * 8];
    int outc = 32 * wave + m;
    const __bf16* w1r = w1b + (size_t)outc * 128 + half * 8;
    const __bf16* w2r = w2b + (size_t)outc * 128 + half * 8;
    f32x16 acc1, acc2;
#pragma unroll
    for (int i = 0; i < 16; i++) { acc1[i] = 0.f; acc2[i] = 0.f; }
#pragma unroll
    for (int kk = 0; kk < 8; kk++) {
        bf16x8 bw1 = *(const bf16x8*)(w1r + kk * 16);
        bf16x8 bw2 = *(const bf16x8*)(w2r + kk * 16);
        acc1 = __builtin_amdgcn_mfma_f32_32x32x16_bf16(a[kk], bw1, acc1, 0, 0, 0);
        acc2 = __builtin_amdgcn_mfma_f32_32x32x16_bf16(a[kk], bw2, acc2, 0, 0, 0);
    }
    float bias1 = b1[outc], bias2 = b2[outc];
#pragma unroll
    for (int reg = 0; reg < 16; reg++) {
        int row = (reg & 3) + 8 * (reg >> 2) + 4 * half;
        float v1 = acc1[reg] + bias1;
        float v2 = acc2[reg] + bias2;
        float g = fast_rcp(1.0f + __expf(-v2));
        float hv = h[(size_t)(r0 + row) * Hdim + outc] + v1 * g;
        dots[row * 132 + outc] = hv;
    }
    __syncthreads();
    // restage h tile as bf16 A-operands
    for (int i = t; i < 32 * 128; i += 256) {
        int r = i >> 7, k = i & 127;
        ybf[r * 136 + k] = (__bf16)dots[r * 132 + k];
    }
    __syncthreads();
    if (wave < 2) {  // decoder GEMM: 32 rows x 64 outs, K=128
        bf16x8 a2[8];
#pragma unroll
        for (int kk = 0; kk < 8; kk++)
            a2[kk] = *(const bf16x8*)&ybf[m * 136 + kk * 16 + half * 8];
        int oc = 32 * wave + m;  // 0..63
        const __bf16* wr = decb + (size_t)oc * 128 + half * 8;
        f32x16 acc;
#pragma unroll
        for (int i = 0; i < 16; i++) acc[i] = 0.f;
#pragma unroll
        for (int kk = 0; kk < 8; kk++) {
            bf16x8 bw = *(const bf16x8*)(wr + kk * 16);
            acc = __builtin_amdgcn_mfma_f32_32x32x16_bf16(a2[kk], bw, acc, 0, 0, 0);
        }
        float bo = dec_bias[oc];
#pragma unroll
        for (int reg = 0; reg < 16; reg++) {
            int row = (reg & 3) + 8 * (reg >> 2) + 4 * half;
            out[(size_t)(r0 + row) * 64 + oc] = acc[reg] + bo;
        }
    }
}

extern "C" void kernel_launch(void* const* d_in, const int* in_sizes, int n_in,
                              void* d_out, int out_size, void* d_ws, size_t ws_size,
                              hipStream_t stream) {
    const float* x      = (const float*)d_in[0];
    const float* enc_w  = (const float*)d_in[2];
    const float* enc_b  = (const float*)d_in[3];
    const float* dec_w  = (const float*)d_in[4];
    const float* dec_b  = (const float*)d_in[5];
    const float* lam_re = (const float*)d_in[6];
    const float* lam_im = (const float*)d_in[7];
    const float* p_re   = (const float*)d_in[8];
    const float* p_im   = (const float*)d_in[9];
    const float* b_re   = (const float*)d_in[10];
    const float* b_im   = (const float*)d_in[11];
    const float* c_re   = (const float*)d_in[12];
    const float* c_im   = (const float*)d_in[13];
    const float* dvec   = (const float*)d_in[14];
    const float* lstep  = (const float*)d_in[15];
    const float* norm_w = (const float*)d_in[16];
    const float* norm_b = (const float*)d_in[17];
    const float* w1     = (const float*)d_in[18];
    const float* b1     = (const float*)d_in[19];
    const float* w2     = (const float*)d_in[20];
    const float* b2     = (const float*)d_in[21];
    float* out = (float*)d_out;

    char* ws = (char*)d_ws;
    float2* tw  = (float2*)ws;  ws += 2048 * sizeof(float2);
    float*  h   = (float*)ws;   ws += (size_t)Bsz * Lseq * Hdim * sizeof(float);
    float*  hnT = (float*)ws;   ws += (size_t)Bsz * Lseq * Hdim * sizeof(float);
    float2* atr = (float2*)ws;  ws += (size_t)NLAYERS * Hdim * Lseq * sizeof(float2);
    float2* Kd1 = (float2*)ws;  ws += (size_t)NLAYERS * Hdim * 4096 * sizeof(float2);
    __bf16* wbf = (__bf16*)ws;  ws += (size_t)NLAYERS * 2 * Hdim * Hdim * sizeof(__bf16);
    __bf16* dbf = (__bf16*)ws;  ws += (size_t)64 * Hdim * sizeof(__bf16);

    const int nrows = Bsz * Lseq;  // 16384

    prep_kernel<<<296 + 2048, 256, 0, stream>>>(
        lam_re, lam_im, p_re, p_im, b_re, b_im, c_re, c_im, lstep, w1, w2, dec_w,
        tw, wbf, dbf, atr);
    kfft_enc_kernel<<<512 + nrows / 16, 256, 0, stream>>>(
        atr, Kd1, tw, x, enc_w, enc_b, norm_w, norm_b, h, hnT);
    for (int L = 0; L < NLAYERS; L++) {
        conv_kernel<<<dim3(Hdim, Bsz / 2), 256, 0, stream>>>(
            hnT, Kd1 + (size_t)L * Hdim * 4096, dvec + L * Hdim, tw);
        const __bf16* w1bL = wbf + (size_t)L * 2 * Hdim * Hdim;
        const __bf16* w2bL = w1bL + Hdim * Hdim;
        if (L < NLAYERS - 1) {
            const float* nwn = norm_w + (L + 1) * Hdim;
            const float* nbn = norm_b + (L + 1) * Hdim;
            mlp_kernel<<<nrows / 32, 256, 0, stream>>>(hnT, h, hnT, w1bL, w2bL,
                                                       b1 + L * Hdim, b2 + L * Hdim,
                                                       nwn, nbn);
        } else {
            mlpdec_kernel<<<nrows / 32, 256, 0, stream>>>(hnT, h, w1bL, w2bL,
                                                          b1 + L * Hdim, b2 + L * Hdim,
                                                          dbf, dec_b, out);
        }
    }
}